// Round 4
// baseline (6012.618 us; speedup 1.0000x reference)
//
#include <hip/hip_runtime.h>

static constexpr int NMv  = 256;
static constexpr int PIXv = 65536;   // 256*256

// ---------- float <-> sortable key (for atomicMax on floats) ----------
__device__ __forceinline__ unsigned fkey(float f){
    unsigned b = __float_as_uint(f);
    return (b & 0x80000000u) ? ~b : (b | 0x80000000u);
}
__device__ __forceinline__ float unfkey(unsigned k){
    unsigned b = (k & 0x80000000u) ? (k & 0x7fffffffu) : ~k;
    return __uint_as_float(b);
}

// ---------- build Z0 = concat([Za, swap(Zb)], 0), shape (8,1,256,256) ----------
__global__ __launch_bounds__(256) void k_prep(const float* __restrict__ Za,
                                              const float* __restrict__ Zb,
                                              float* __restrict__ Z){
    __shared__ float tile[32][33];
    int b  = blockIdx.z;
    int tx = threadIdx.x, ty = threadIdx.y;     // 32 x 8
    int n0 = blockIdx.y * 32, m0 = blockIdx.x * 32;
    if (b < 4){
        const float* src = Za + (size_t)b * PIXv;
        float*       dst = Z  + (size_t)b * PIXv;
        for (int j = 0; j < 32; j += 8){
            int n = n0 + ty + j;
            dst[n * NMv + m0 + tx] = src[n * NMv + m0 + tx];
        }
    } else {
        const float* src = Zb + (size_t)(b - 4) * PIXv;
        for (int j = 0; j < 32; j += 8)
            tile[ty + j][tx] = src[(m0 + ty + j) * NMv + n0 + tx];
        __syncthreads();
        float* dst = Z + (size_t)b * PIXv;
        for (int j = 0; j < 32; j += 8)
            dst[(n0 + ty + j) * NMv + m0 + tx] = tile[tx][ty + j];
    }
}

// ---------- fused z = Wm*X + bm with axis-max reduction (never materialize z) ----------
// grid (4,16,8) block 256.
//  b<4 : max over n, out (c,m).  blockIdx.x = m-tile(64), blockIdx.y = n-chunk(16 rows)
//  b>=4: max over m, out (c,n).  blockIdx.x = n-tile(64), blockIdx.y = m-chunk(16 cols)
template<int C>
__global__ __launch_bounds__(256) void k_zmax(const float* __restrict__ Z,
                                              const float* __restrict__ Wm,
                                              const float* __restrict__ bm,
                                              unsigned* __restrict__ zkey){
    constexpr int K2 = 2 * C;
    __shared__ float Wms[K2 * 64];     // [k][c] (transposed: conflict-free per-k reads)
    __shared__ float Xs[K2 * 68];      // rows: stride 68 (64m + pad4). cols: stride 20.
    int b = blockIdx.z;
    int t = threadIdx.x;
    for (int i = t; i < 64 * K2; i += 256){
        int c = i / K2, k = i % K2;
        Wms[k * 64 + c] = Wm[i];
    }
    const float* Z0 = Z + (size_t)b       * C * PIXv;
    const float* Z1 = Z + (size_t)(b ^ 4) * C * PIXv;

    if (b < 4){
        int m0 = blockIdx.x * 64, n0 = blockIdx.y * 16;
        int c0 = (t >> 3) * 2, mg = t & 7;          // 2 channels, 8 m's
        float mx[2][8];
        #pragma unroll
        for (int a2 = 0; a2 < 2; a2++)
            #pragma unroll
            for (int j = 0; j < 8; j++) mx[a2][j] = -3.4e38f;
        for (int ni = 0; ni < 16; ni++){
            int n = n0 + ni;
            __syncthreads();
            for (int s = t; s < K2 * 16; s += 256){
                int k = s >> 4, m4 = (s & 15) * 4;
                const float* src = (k < C ? Z0 + (size_t)k * PIXv
                                          : Z1 + (size_t)(k - C) * PIXv) + n * NMv + m0 + m4;
                *(float4*)&Xs[k * 68 + m4] = *(const float4*)src;
            }
            __syncthreads();
            float acc[2][8];
            #pragma unroll
            for (int a2 = 0; a2 < 2; a2++)
                #pragma unroll
                for (int j = 0; j < 8; j++) acc[a2][j] = 0.f;
            #pragma unroll 8
            for (int k = 0; k < K2; k++){
                const float2 w  = *(const float2*)&Wms[k * 64 + c0];
                const float4 x0 = *(const float4*)&Xs[k * 68 + mg * 8];
                const float4 x1 = *(const float4*)&Xs[k * 68 + mg * 8 + 4];
                acc[0][0] += w.x * x0.x; acc[0][1] += w.x * x0.y;
                acc[0][2] += w.x * x0.z; acc[0][3] += w.x * x0.w;
                acc[0][4] += w.x * x1.x; acc[0][5] += w.x * x1.y;
                acc[0][6] += w.x * x1.z; acc[0][7] += w.x * x1.w;
                acc[1][0] += w.y * x0.x; acc[1][1] += w.y * x0.y;
                acc[1][2] += w.y * x0.z; acc[1][3] += w.y * x0.w;
                acc[1][4] += w.y * x1.x; acc[1][5] += w.y * x1.y;
                acc[1][6] += w.y * x1.z; acc[1][7] += w.y * x1.w;
            }
            #pragma unroll
            for (int a2 = 0; a2 < 2; a2++)
                #pragma unroll
                for (int j = 0; j < 8; j++) mx[a2][j] = fmaxf(mx[a2][j], acc[a2][j]);
        }
        #pragma unroll
        for (int a2 = 0; a2 < 2; a2++){
            float bmv = bm[c0 + a2];
            #pragma unroll
            for (int j = 0; j < 8; j++)
                atomicMax(&zkey[((size_t)b * 64 + c0 + a2) * NMv + m0 + mg * 8 + j],
                          fkey(mx[a2][j] + bmv));
        }
    } else {
        int n0 = blockIdx.x * 64, mq0 = blockIdx.y * 16;
        int c = t >> 2, mg = t & 3;                 // 1 channel, 4 m's
        float bmv = bm[c];
        for (int ni = 0; ni < 64; ni++){
            int n = n0 + ni;
            __syncthreads();
            for (int s = t; s < K2 * 4; s += 256){
                int k = s >> 2, m4 = (s & 3) * 4;
                const float* src = (k < C ? Z0 + (size_t)k * PIXv
                                          : Z1 + (size_t)(k - C) * PIXv) + n * NMv + mq0 + m4;
                *(float4*)&Xs[k * 20 + m4] = *(const float4*)src;
            }
            __syncthreads();
            float a0 = 0.f, a1 = 0.f, a2 = 0.f, a3 = 0.f;
            #pragma unroll 8
            for (int k = 0; k < K2; k++){
                const float  w = Wms[k * 64 + c];
                const float4 x = *(const float4*)&Xs[k * 20 + mg * 4];
                a0 += w * x.x; a1 += w * x.y; a2 += w * x.z; a3 += w * x.w;
            }
            float mx4 = fmaxf(fmaxf(a0, a1), fmaxf(a2, a3));
            mx4 = fmaxf(mx4, __shfl_xor(mx4, 1));
            mx4 = fmaxf(mx4, __shfl_xor(mx4, 2));
            if (mg == 0)
                atomicMax(&zkey[((size_t)b * 64 + c) * NMv + n], fkey(mx4 + bmv));
        }
    }
}

// ---------- zmaxW[b,oc,p] = sum_c W[oc, 2C+c] * zmax[b,c,p] ----------
__global__ __launch_bounds__(256) void k_zmaxw(const unsigned* __restrict__ zkey,
                                               const float* __restrict__ W, int Wst,
                                               float* __restrict__ zmaxW){
    int oc = blockIdx.x, b = blockIdx.y, p = threadIdx.x;
    const float* wrow = W + (size_t)oc * Wst + (Wst - 64);
    float s = 0.f;
    #pragma unroll 8
    for (int c = 0; c < 64; c++)
        s += wrow[c] * unfkey(zkey[((size_t)b * 64 + c) * NMv + p]);
    zmaxW[((size_t)b * 32 + oc) * NMv + p] = s;
}

// ---------- y = W[:, :2C]*X + zmaxW ; accumulate BN stats ----------
// grid (256 rows, 8 b), block 256. thread: 4 pixels (p4*4..+3) x 8 oc (og*8..+7)
template<int C>
__global__ __launch_bounds__(256) void k_conv(const float* __restrict__ Z,
                                              const float* __restrict__ Wl,
                                              const float* __restrict__ zmaxW,
                                              float* __restrict__ Y,
                                              float* __restrict__ stats){
    constexpr int K2 = 2 * C;
    constexpr int KC = (K2 < 16) ? K2 : 16;
    __shared__ float Ws[K2 * 32];       // [k][oc]
    __shared__ float Xs[KC * 256];      // [kk][m]
    int b   = blockIdx.y;
    int row = blockIdx.x;
    int t   = threadIdx.x;
    int p4  = t & 63, og = t >> 6;
    for (int i = t; i < K2 * 32; i += 256){
        int k = i >> 5, oc = i & 31;
        Ws[i] = Wl[(size_t)oc * (K2 + 64) + k];
    }
    const float* Z0 = Z + ((size_t)b       * C) * PIXv + (size_t)row * NMv;
    const float* Z1 = Z + ((size_t)(b ^ 4) * C) * PIXv + (size_t)row * NMv;
    float acc[4][8];
    #pragma unroll
    for (int j = 0; j < 4; j++)
        #pragma unroll
        for (int o = 0; o < 8; o++) acc[j][o] = 0.f;

    for (int kc = 0; kc < K2; kc += KC){
        __syncthreads();
        for (int s = t; s < KC * 64; s += 256){
            int k = kc + (s >> 6), m4 = (s & 63) * 4;
            const float* src = (k < C ? Z0 + (size_t)k * PIXv
                                      : Z1 + (size_t)(k - C) * PIXv) + m4;
            *(float4*)&Xs[(s >> 6) * 256 + m4] = *(const float4*)src;
        }
        __syncthreads();
        #pragma unroll 4
        for (int kk = 0; kk < KC; kk++){
            const float4 xv = *(const float4*)&Xs[kk * 256 + p4 * 4];
            const float4 wa = *(const float4*)&Ws[(kc + kk) * 32 + og * 8];
            const float4 wb = *(const float4*)&Ws[(kc + kk) * 32 + og * 8 + 4];
            const float xx[4] = {xv.x, xv.y, xv.z, xv.w};
            const float ww[8] = {wa.x, wa.y, wa.z, wa.w, wb.x, wb.y, wb.z, wb.w};
            #pragma unroll
            for (int j = 0; j < 4; j++)
                #pragma unroll
                for (int o = 0; o < 8; o++)
                    acc[j][o] += xx[j] * ww[o];
        }
    }
    // add max-part contribution
    if (b < 4){
        #pragma unroll
        for (int o = 0; o < 8; o++){
            float4 zw = *(const float4*)&zmaxW[((size_t)b * 32 + og * 8 + o) * NMv + p4 * 4];
            acc[0][o] += zw.x; acc[1][o] += zw.y; acc[2][o] += zw.z; acc[3][o] += zw.w;
        }
    } else {
        #pragma unroll
        for (int o = 0; o < 8; o++){
            float zw = zmaxW[((size_t)b * 32 + og * 8 + o) * NMv + row];
            acc[0][o] += zw; acc[1][o] += zw; acc[2][o] += zw; acc[3][o] += zw;
        }
    }
    // write y
    float* yb = Y + ((size_t)b * 32 + og * 8) * PIXv + (size_t)row * NMv + p4 * 4;
    #pragma unroll
    for (int o = 0; o < 8; o++){
        float4 v = make_float4(acc[0][o], acc[1][o], acc[2][o], acc[3][o]);
        *(float4*)(yb + (size_t)o * PIXv) = v;
    }
    // BN stats: wave covers full row (64 lanes * 4 px) for its 8 channels
    #pragma unroll
    for (int o = 0; o < 8; o++){
        float s1 = acc[0][o] + acc[1][o] + acc[2][o] + acc[3][o];
        float s2 = acc[0][o] * acc[0][o] + acc[1][o] * acc[1][o] +
                   acc[2][o] * acc[2][o] + acc[3][o] * acc[3][o];
        #pragma unroll
        for (int d = 32; d > 0; d >>= 1){
            s1 += __shfl_down(s1, d);
            s2 += __shfl_down(s2, d);
        }
        if ((t & 63) == 0){
            atomicAdd(&stats[og * 8 + o], s1);
            atomicAdd(&stats[32 + og * 8 + o], s2);
        }
    }
}

// ---------- BN finalize (in-block) + apply + PReLU + residual ----------
__global__ __launch_bounds__(256) void k_bnapply(const float* __restrict__ Y,
                                                 const float* __restrict__ stats,
                                                 const float* __restrict__ g,
                                                 const float* __restrict__ be,
                                                 const float* __restrict__ keep_in,
                                                 const float* __restrict__ aptr,
                                                 float* __restrict__ Zout,
                                                 float* __restrict__ keep_out){
    __shared__ float s_sc[32], s_sh[32];
    if (threadIdx.x < 32){
        int c = threadIdx.x;
        const float inv = 1.f / (8.f * PIXv);
        float mu  = stats[c] * inv;
        float var = stats[32 + c] * inv - mu * mu;
        float sc  = g[c] * rsqrtf(var + 1e-5f);
        s_sc[c] = sc;
        s_sh[c] = be[c] - mu * sc;
    }
    __syncthreads();
    const float al = *aptr;
    const size_t tot = (size_t)8 * 32 * PIXv / 4;
    for (size_t i = (size_t)blockIdx.x * 256 + threadIdx.x; i < tot;
         i += (size_t)gridDim.x * 256){
        int c = (int)((i >> 14) & 31);
        float4 y = ((const float4*)Y)[i];
        float sc = s_sc[c], sh = s_sh[c];
        float4 v;
        v.x = sc * y.x + sh; v.y = sc * y.y + sh;
        v.z = sc * y.z + sh; v.w = sc * y.w + sh;
        v.x = v.x >= 0.f ? v.x : al * v.x;
        v.y = v.y >= 0.f ? v.y : al * v.y;
        v.z = v.z >= 0.f ? v.z : al * v.z;
        v.w = v.w >= 0.f ? v.w : al * v.w;
        if (keep_in){
            float4 kz = ((const float4*)keep_in)[i];
            v.x += kz.x; v.y += kz.y; v.z += kz.z; v.w += kz.w;
        }
        ((float4*)Zout)[i] = v;
        if (keep_out) ((float4*)keep_out)[i] = v;
    }
}

// ---------- final 1x1 conv (Wf) + stats ----------
__global__ __launch_bounds__(256) void k_final(const float* __restrict__ Z,
                                               const float* __restrict__ Wf,
                                               float* __restrict__ T,
                                               float* __restrict__ fstats){
    int b = blockIdx.y;
    size_t base = (size_t)blockIdx.x * 1024 + (size_t)threadIdx.x * 4;
    const float* Z0 = Z + (size_t)b       * 32 * PIXv + base;
    const float* Z1 = Z + (size_t)(b ^ 4) * 32 * PIXv + base;
    float4 acc = make_float4(0.f, 0.f, 0.f, 0.f);
    #pragma unroll 8
    for (int c = 0; c < 32; c++){
        float w0 = Wf[c], w1 = Wf[32 + c];
        float4 x0 = *(const float4*)(Z0 + (size_t)c * PIXv);
        float4 x1 = *(const float4*)(Z1 + (size_t)c * PIXv);
        acc.x += w0 * x0.x + w1 * x1.x;
        acc.y += w0 * x0.y + w1 * x1.y;
        acc.z += w0 * x0.z + w1 * x1.z;
        acc.w += w0 * x0.w + w1 * x1.w;
    }
    *(float4*)(T + (size_t)b * PIXv + base) = acc;
    float a1 = acc.x + acc.y + acc.z + acc.w;
    float a2 = acc.x * acc.x + acc.y * acc.y + acc.z * acc.z + acc.w * acc.w;
    #pragma unroll
    for (int d = 32; d > 0; d >>= 1){
        a1 += __shfl_down(a1, d);
        a2 += __shfl_down(a2, d);
    }
    if ((threadIdx.x & 63) == 0){
        atomicAdd(&fstats[0], a1);
        atomicAdd(&fstats[1], a2);
    }
}

// ---------- final BN (in-block) + m0/m1/mm ----------
__global__ __launch_bounds__(256) void k_mm(const float* __restrict__ T,
                                            const float* __restrict__ fstats,
                                            const float* __restrict__ gf,
                                            const float* __restrict__ bf,
                                            float* __restrict__ out,
                                            float* __restrict__ MMb){
    const float inv = 1.f / (8.f * PIXv);
    float mu  = fstats[0] * inv;
    float var = fstats[1] * inv - mu * mu;
    float sc  = gf[0] * rsqrtf(var + 1e-5f);
    float sh  = bf[0] - mu * sc;
    size_t e = ((size_t)blockIdx.x * 256 + threadIdx.x) * 4;    // over 4*PIX
    float4 t0 = *(const float4*)(T + e);
    float4 t1 = *(const float4*)(T + (size_t)4 * PIXv + e);
    float4 m0, m1, mv;
    m0.x = sc * t0.x + sh; m0.y = sc * t0.y + sh; m0.z = sc * t0.z + sh; m0.w = sc * t0.w + sh;
    m1.x = sc * t1.x + sh; m1.y = sc * t1.y + sh; m1.z = sc * t1.z + sh; m1.w = sc * t1.w + sh;
    mv.x = 0.5f * (m0.x + m1.x); mv.y = 0.5f * (m0.y + m1.y);
    mv.z = 0.5f * (m0.z + m1.z); mv.w = 0.5f * (m0.w + m1.w);
    *(float4*)(out + (size_t)4 * PIXv + e) = m0;
    *(float4*)(out + (size_t)8 * PIXv + e) = m1;
    *(float4*)(MMb + e) = mv;
}

// ---------- row softmax stats: one wave per row ----------
__global__ __launch_bounds__(256) void k_rowstats(const float* __restrict__ MMb,
                                                  float* __restrict__ rmax,
                                                  float* __restrict__ rsum){
    int wid = threadIdx.x >> 6, lane = threadIdx.x & 63;
    int r = blockIdx.x * 4 + wid;                    // 0..1023
    const float* p = MMb + (size_t)r * NMv;
    float4 v = *(const float4*)(p + lane * 4);
    float mx = fmaxf(fmaxf(v.x, v.y), fmaxf(v.z, v.w));
    #pragma unroll
    for (int d = 32; d > 0; d >>= 1) mx = fmaxf(mx, __shfl_xor(mx, d));
    float s = expf(v.x - mx) + expf(v.y - mx) + expf(v.z - mx) + expf(v.w - mx);
    #pragma unroll
    for (int d = 32; d > 0; d >>= 1) s += __shfl_xor(s, d);
    if (lane == 0){ rmax[r] = mx; rsum[r] = s; }
}

// ---------- column softmax stats (chunked atomics) ----------
__global__ __launch_bounds__(256) void k_colmax(const float* __restrict__ MMb,
                                                unsigned* __restrict__ ckey){
    int b = blockIdx.y, ch = blockIdx.x, m = threadIdx.x;
    const float* p = MMb + (size_t)b * PIXv + (size_t)ch * 16 * NMv + m;
    float mx = -3.4e38f;
    #pragma unroll
    for (int n = 0; n < 16; n++) mx = fmaxf(mx, p[(size_t)n * NMv]);
    atomicMax(&ckey[b * NMv + m], fkey(mx));
}
__global__ __launch_bounds__(256) void k_colsum(const float* __restrict__ MMb,
                                                const unsigned* __restrict__ ckey,
                                                float* __restrict__ csum){
    int b = blockIdx.y, ch = blockIdx.x, m = threadIdx.x;
    const float* p = MMb + (size_t)b * PIXv + (size_t)ch * 16 * NMv + m;
    float cm = unfkey(ckey[b * NMv + m]);
    float s = 0.f;
    #pragma unroll
    for (int n = 0; n < 16; n++) s += expf(p[(size_t)n * NMv] - cm);
    atomicAdd(&csum[b * NMv + m], s);
}

// ---------- agg = min(row_softmax, col_softmax) ----------
__global__ __launch_bounds__(256) void k_agg(const float* __restrict__ MMb,
                                             const float* __restrict__ rmax,
                                             const float* __restrict__ rsum,
                                             const unsigned* __restrict__ ckey,
                                             const float* __restrict__ csum,
                                             float* __restrict__ out){
    size_t e = ((size_t)blockIdx.x * 256 + threadIdx.x) * 4;
    int r = (int)(e >> 8);
    int b = (int)(e >> 16);
    int m = (int)(e & 255);
    int cb = b * NMv + m;
    float rm = rmax[r], rsi = 1.f / rsum[r];
    float4 v = *(const float4*)(MMb + e);
    float4 o;
    o.x = fminf(expf(v.x - rm) * rsi, expf(v.x - unfkey(ckey[cb + 0])) / csum[cb + 0]);
    o.y = fminf(expf(v.y - rm) * rsi, expf(v.y - unfkey(ckey[cb + 1])) / csum[cb + 1]);
    o.z = fminf(expf(v.z - rm) * rsi, expf(v.z - unfkey(ckey[cb + 2])) / csum[cb + 2]);
    o.w = fminf(expf(v.w - rm) * rsi, expf(v.w - unfkey(ckey[cb + 3])) / csum[cb + 3]);
    *(float4*)(out + e) = o;
}

extern "C" void kernel_launch(void* const* d_in, const int* in_sizes, int n_in,
                              void* d_out, int out_size, void* d_ws, size_t ws_size,
                              hipStream_t stream){
    (void)in_sizes; (void)n_in; (void)out_size; (void)ws_size;
    const float* Za  = (const float*)d_in[0];
    const float* Zb  = (const float*)d_in[1];
    const float* Wm0 = (const float*)d_in[2];
    const float* bm0 = (const float*)d_in[3];
    const float* W0  = (const float*)d_in[4];
    const float* g0  = (const float*)d_in[5];
    const float* be0 = (const float*)d_in[6];
    const float* Wm  = (const float*)d_in[7];
    const float* bm  = (const float*)d_in[8];
    const float* W   = (const float*)d_in[9];
    const float* g   = (const float*)d_in[10];
    const float* be  = (const float*)d_in[11];
    const float* ap  = (const float*)d_in[12];
    const float* Wf  = (const float*)d_in[13];
    const float* gf  = (const float*)d_in[14];
    const float* bf  = (const float*)d_in[15];
    float* out = (float*)d_out;

    size_t off = 0;
    char* wsb = (char*)d_ws;
    auto alloc = [&](size_t bytes) -> void* {
        void* p = wsb + off;
        off += (bytes + 255) & ~(size_t)255;
        return p;
    };
    float*    Zbuf  = (float*)   alloc((size_t)8 * 32 * PIXv * 4);
    float*    Zkeep = (float*)   alloc((size_t)8 * 32 * PIXv * 4);
    float*    Ybuf  = (float*)   alloc((size_t)8 * 32 * PIXv * 4);
    unsigned* zkey  = (unsigned*)alloc((size_t)8 * 64 * NMv * 4);
    float*    zmaxW = (float*)   alloc((size_t)8 * 32 * NMv * 4);
    float*    stats = (float*)   alloc(64 * 4);
    float*    T     = (float*)   alloc((size_t)8 * PIXv * 4);
    float*    fstats= (float*)   alloc(2 * 4);
    float*    MMb   = (float*)   alloc((size_t)4 * PIXv * 4);
    float*    rmaxb = (float*)   alloc(1024 * 4);
    float*    rsumb = (float*)   alloc(1024 * 4);
    unsigned* ckey  = (unsigned*)alloc(1024 * 4);
    float*    csum  = (float*)   alloc(1024 * 4);

    // Z0
    k_prep<<<dim3(8, 8, 8), dim3(32, 8), 0, stream>>>(Za, Zb, Zbuf);

    for (int i = 0; i < 6; i++){
        const float *Wm_l, *bm_l, *W_l, *g_l, *be_l;
        int C;
        if (i == 0){ Wm_l = Wm0; bm_l = bm0; W_l = W0; g_l = g0; be_l = be0; C = 1; }
        else {
            Wm_l = Wm + (size_t)(i - 1) * 64 * 64;
            bm_l = bm + (size_t)(i - 1) * 64;
            W_l  = W  + (size_t)(i - 1) * 32 * 128;
            g_l  = g  + (size_t)(i - 1) * 32;
            be_l = be + (size_t)(i - 1) * 32;
            C = 32;
        }
        hipMemsetAsync(zkey, 0, (size_t)8 * 64 * NMv * 4, stream);
        if (C == 1) k_zmax<1 ><<<dim3(4, 16, 8), 256, 0, stream>>>(Zbuf, Wm_l, bm_l, zkey);
        else        k_zmax<32><<<dim3(4, 16, 8), 256, 0, stream>>>(Zbuf, Wm_l, bm_l, zkey);
        k_zmaxw<<<dim3(32, 8), 256, 0, stream>>>(zkey, W_l, 2 * C + 64, zmaxW);
        hipMemsetAsync(stats, 0, 64 * 4, stream);
        if (C == 1) k_conv<1 ><<<dim3(256, 8), 256, 0, stream>>>(Zbuf, W_l, zmaxW, Ybuf, stats);
        else        k_conv<32><<<dim3(256, 8), 256, 0, stream>>>(Zbuf, W_l, zmaxW, Ybuf, stats);
        bool addk   = (i == 2 || i == 4);
        bool storek = (i % 2 == 0);
        k_bnapply<<<4096, 256, 0, stream>>>(Ybuf, stats, g_l, be_l,
                                            addk ? Zkeep : (const float*)nullptr, ap,
                                            Zbuf, storek ? Zkeep : (float*)nullptr);
    }

    hipMemsetAsync(fstats, 0, 2 * 4, stream);
    k_final<<<dim3(64, 8), 256, 0, stream>>>(Zbuf, Wf, T, fstats);
    k_mm<<<256, 256, 0, stream>>>(T, fstats, gf, bf, out, MMb);
    k_rowstats<<<256, 256, 0, stream>>>(MMb, rmaxb, rsumb);
    hipMemsetAsync(ckey, 0, 1024 * 4, stream);
    hipMemsetAsync(csum, 0, 1024 * 4, stream);
    k_colmax<<<dim3(16, 4), 256, 0, stream>>>(MMb, ckey);
    k_colsum<<<dim3(16, 4), 256, 0, stream>>>(MMb, ckey, csum);
    k_agg<<<256, 256, 0, stream>>>(MMb, rmaxb, rsumb, ckey, csum, out);
}

// Round 7
// 1393.252 us; speedup vs baseline: 4.3155x; 4.3155x over previous
//
#include <hip/hip_runtime.h>

static constexpr int NMv  = 256;
static constexpr int PIXv = 65536;   // 256*256

// ---------- float <-> sortable key (for atomicMax on floats) ----------
__device__ __forceinline__ unsigned fkey(float f){
    unsigned b = __float_as_uint(f);
    return (b & 0x80000000u) ? ~b : (b | 0x80000000u);
}
__device__ __forceinline__ float unfkey(unsigned k){
    unsigned b = (k & 0x80000000u) ? (k & 0x7fffffffu) : ~k;
    return __uint_as_float(b);
}

// ---------- build Z0 = concat([Za, swap(Zb)], 0), shape (8,1,256,256) ----------
__global__ __launch_bounds__(256) void k_prep(const float* __restrict__ Za,
                                              const float* __restrict__ Zb,
                                              float* __restrict__ Z){
    __shared__ float tile[32][33];
    int b  = blockIdx.z;
    int tx = threadIdx.x, ty = threadIdx.y;     // 32 x 8
    int n0 = blockIdx.y * 32, m0 = blockIdx.x * 32;
    if (b < 4){
        const float* src = Za + (size_t)b * PIXv;
        float*       dst = Z  + (size_t)b * PIXv;
        for (int j = 0; j < 32; j += 8){
            int n = n0 + ty + j;
            dst[n * NMv + m0 + tx] = src[n * NMv + m0 + tx];
        }
    } else {
        const float* src = Zb + (size_t)(b - 4) * PIXv;
        for (int j = 0; j < 32; j += 8)
            tile[ty + j][tx] = src[(m0 + ty + j) * NMv + n0 + tx];
        __syncthreads();
        float* dst = Z + (size_t)b * PIXv;
        for (int j = 0; j < 32; j += 8)
            dst[(n0 + ty + j) * NMv + m0 + tx] = tile[tx][ty + j];
    }
}

// ---------- fused z = Wm*X + bm with axis-max reduction (never materialize z) ----------
// grid (4,16,8) block 256.
//  b<4 : max over n, out (c,m).  blockIdx.x = m-tile(64), blockIdx.y = n-chunk(16 rows)
//  b>=4: max over m, out (c,n).  blockIdx.x = n-tile(64), blockIdx.y = m-chunk(16 cols)
template<int C>
__global__ __launch_bounds__(256) void k_zmax(const float* __restrict__ Z,
                                              const float* __restrict__ Wm,
                                              const float* __restrict__ bm,
                                              unsigned* __restrict__ zkey){
    constexpr int K2 = 2 * C;
    __shared__ float Wms[K2 * 64];     // [k][c] (transposed: conflict-free per-k reads)
    __shared__ float Xs[K2 * 68];      // rows: stride 68 (64m + pad4). cols: stride 20.
    int b = blockIdx.z;
    int t = threadIdx.x;
    for (int i = t; i < 64 * K2; i += 256){
        int c = i / K2, k = i % K2;
        Wms[k * 64 + c] = Wm[i];
    }
    const float* Z0 = Z + (size_t)b       * C * PIXv;
    const float* Z1 = Z + (size_t)(b ^ 4) * C * PIXv;

    if (b < 4){
        int m0 = blockIdx.x * 64, n0 = blockIdx.y * 16;
        int c0 = (t >> 3) * 2, mg = t & 7;          // 2 channels, 8 m's
        float mx[2][8];
        #pragma unroll
        for (int a2 = 0; a2 < 2; a2++)
            #pragma unroll
            for (int j = 0; j < 8; j++) mx[a2][j] = -3.4e38f;
        for (int ni = 0; ni < 16; ni++){
            int n = n0 + ni;
            __syncthreads();
            for (int s = t; s < K2 * 16; s += 256){
                int k = s >> 4, m4 = (s & 15) * 4;
                const float* src = (k < C ? Z0 + (size_t)k * PIXv
                                          : Z1 + (size_t)(k - C) * PIXv) + n * NMv + m0 + m4;
                *(float4*)&Xs[k * 68 + m4] = *(const float4*)src;
            }
            __syncthreads();
            float acc[2][8];
            #pragma unroll
            for (int a2 = 0; a2 < 2; a2++)
                #pragma unroll
                for (int j = 0; j < 8; j++) acc[a2][j] = 0.f;
            #pragma unroll 8
            for (int k = 0; k < K2; k++){
                const float2 w  = *(const float2*)&Wms[k * 64 + c0];
                const float4 x0 = *(const float4*)&Xs[k * 68 + mg * 8];
                const float4 x1 = *(const float4*)&Xs[k * 68 + mg * 8 + 4];
                acc[0][0] += w.x * x0.x; acc[0][1] += w.x * x0.y;
                acc[0][2] += w.x * x0.z; acc[0][3] += w.x * x0.w;
                acc[0][4] += w.x * x1.x; acc[0][5] += w.x * x1.y;
                acc[0][6] += w.x * x1.z; acc[0][7] += w.x * x1.w;
                acc[1][0] += w.y * x0.x; acc[1][1] += w.y * x0.y;
                acc[1][2] += w.y * x0.z; acc[1][3] += w.y * x0.w;
                acc[1][4] += w.y * x1.x; acc[1][5] += w.y * x1.y;
                acc[1][6] += w.y * x1.z; acc[1][7] += w.y * x1.w;
            }
            #pragma unroll
            for (int a2 = 0; a2 < 2; a2++)
                #pragma unroll
                for (int j = 0; j < 8; j++) mx[a2][j] = fmaxf(mx[a2][j], acc[a2][j]);
        }
        #pragma unroll
        for (int a2 = 0; a2 < 2; a2++){
            float bmv = bm[c0 + a2];
            #pragma unroll
            for (int j = 0; j < 8; j++)
                atomicMax(&zkey[((size_t)b * 64 + c0 + a2) * NMv + m0 + mg * 8 + j],
                          fkey(mx[a2][j] + bmv));
        }
    } else {
        int n0 = blockIdx.x * 64, mq0 = blockIdx.y * 16;
        int c = t >> 2, mg = t & 3;                 // 1 channel, 4 m's
        float bmv = bm[c];
        for (int ni = 0; ni < 64; ni++){
            int n = n0 + ni;
            __syncthreads();
            for (int s = t; s < K2 * 4; s += 256){
                int k = s >> 2, m4 = (s & 3) * 4;
                const float* src = (k < C ? Z0 + (size_t)k * PIXv
                                          : Z1 + (size_t)(k - C) * PIXv) + n * NMv + mq0 + m4;
                *(float4*)&Xs[k * 20 + m4] = *(const float4*)src;
            }
            __syncthreads();
            float a0 = 0.f, a1 = 0.f, a2 = 0.f, a3 = 0.f;
            #pragma unroll 8
            for (int k = 0; k < K2; k++){
                const float  w = Wms[k * 64 + c];
                const float4 x = *(const float4*)&Xs[k * 20 + mg * 4];
                a0 += w * x.x; a1 += w * x.y; a2 += w * x.z; a3 += w * x.w;
            }
            float mx4 = fmaxf(fmaxf(a0, a1), fmaxf(a2, a3));
            mx4 = fmaxf(mx4, __shfl_xor(mx4, 1));
            mx4 = fmaxf(mx4, __shfl_xor(mx4, 2));
            if (mg == 0)
                atomicMax(&zkey[((size_t)b * 64 + c) * NMv + n], fkey(mx4 + bmv));
        }
    }
}

// ---------- zmaxW[b,oc,p] = sum_c W[oc, 2C+c] * zmax[b,c,p] ----------
__global__ __launch_bounds__(256) void k_zmaxw(const unsigned* __restrict__ zkey,
                                               const float* __restrict__ W, int Wst,
                                               float* __restrict__ zmaxW){
    int oc = blockIdx.x, b = blockIdx.y, p = threadIdx.x;
    const float* wrow = W + (size_t)oc * Wst + (Wst - 64);
    float s = 0.f;
    #pragma unroll 8
    for (int c = 0; c < 64; c++)
        s += wrow[c] * unfkey(zkey[((size_t)b * 64 + c) * NMv + p]);
    zmaxW[((size_t)b * 32 + oc) * NMv + p] = s;
}

// ---------- y = W[:, :2C]*X + zmaxW ; per-block BN partials (NO same-address atomics) ----------
// grid (256 rows, 8 b), block 256. thread: 4 pixels (p4*4..+3) x 8 oc (og*8..+7)
// pstats layout: [64 rows][2048 blocks]; row r<32: sum of channel r, r>=32: sumsq of r-32.
template<int C>
__global__ __launch_bounds__(256) void k_conv(const float* __restrict__ Z,
                                              const float* __restrict__ Wl,
                                              const float* __restrict__ zmaxW,
                                              float* __restrict__ Y,
                                              float* __restrict__ pstats){
    constexpr int K2 = 2 * C;
    constexpr int KC = (K2 < 16) ? K2 : 16;
    __shared__ float Ws[K2 * 32];       // [k][oc]
    __shared__ float Xs[KC * 256];      // [kk][m]
    int b   = blockIdx.y;
    int row = blockIdx.x;
    int t   = threadIdx.x;
    int p4  = t & 63, og = t >> 6;
    for (int i = t; i < K2 * 32; i += 256){
        int k = i >> 5, oc = i & 31;
        Ws[i] = Wl[(size_t)oc * (K2 + 64) + k];
    }
    const float* Z0 = Z + ((size_t)b       * C) * PIXv + (size_t)row * NMv;
    const float* Z1 = Z + ((size_t)(b ^ 4) * C) * PIXv + (size_t)row * NMv;
    float acc[4][8];
    #pragma unroll
    for (int j = 0; j < 4; j++)
        #pragma unroll
        for (int o = 0; o < 8; o++) acc[j][o] = 0.f;

    for (int kc = 0; kc < K2; kc += KC){
        __syncthreads();
        for (int s = t; s < KC * 64; s += 256){
            int k = kc + (s >> 6), m4 = (s & 63) * 4;
            const float* src = (k < C ? Z0 + (size_t)k * PIXv
                                      : Z1 + (size_t)(k - C) * PIXv) + m4;
            *(float4*)&Xs[(s >> 6) * 256 + m4] = *(const float4*)src;
        }
        __syncthreads();
        #pragma unroll 4
        for (int kk = 0; kk < KC; kk++){
            const float4 xv = *(const float4*)&Xs[kk * 256 + p4 * 4];
            const float4 wa = *(const float4*)&Ws[(kc + kk) * 32 + og * 8];
            const float4 wb = *(const float4*)&Ws[(kc + kk) * 32 + og * 8 + 4];
            const float xx[4] = {xv.x, xv.y, xv.z, xv.w};
            const float ww[8] = {wa.x, wa.y, wa.z, wa.w, wb.x, wb.y, wb.z, wb.w};
            #pragma unroll
            for (int j = 0; j < 4; j++)
                #pragma unroll
                for (int o = 0; o < 8; o++)
                    acc[j][o] += xx[j] * ww[o];
        }
    }
    // add max-part contribution
    if (b < 4){
        #pragma unroll
        for (int o = 0; o < 8; o++){
            float4 zw = *(const float4*)&zmaxW[((size_t)b * 32 + og * 8 + o) * NMv + p4 * 4];
            acc[0][o] += zw.x; acc[1][o] += zw.y; acc[2][o] += zw.z; acc[3][o] += zw.w;
        }
    } else {
        #pragma unroll
        for (int o = 0; o < 8; o++){
            float zw = zmaxW[((size_t)b * 32 + og * 8 + o) * NMv + row];
            acc[0][o] += zw; acc[1][o] += zw; acc[2][o] += zw; acc[3][o] += zw;
        }
    }
    // write y
    float* yb = Y + ((size_t)b * 32 + og * 8) * PIXv + (size_t)row * NMv + p4 * 4;
    #pragma unroll
    for (int o = 0; o < 8; o++){
        float4 v = make_float4(acc[0][o], acc[1][o], acc[2][o], acc[3][o]);
        *(float4*)(yb + (size_t)o * PIXv) = v;
    }
    // BN partials: each wave owns channels og*8..og*8+7 exclusively; wave covers the
    // full row (64 lanes * 4 px). lane0 writes the per-block partial -> no contention.
    int blk = b * 256 + row;                  // [0, 2048)
    #pragma unroll
    for (int o = 0; o < 8; o++){
        float s1 = acc[0][o] + acc[1][o] + acc[2][o] + acc[3][o];
        float s2 = acc[0][o] * acc[0][o] + acc[1][o] * acc[1][o] +
                   acc[2][o] * acc[2][o] + acc[3][o] * acc[3][o];
        #pragma unroll
        for (int d = 32; d > 0; d >>= 1){
            s1 += __shfl_down(s1, d);
            s2 += __shfl_down(s2, d);
        }
        if ((t & 63) == 0){
            int c = og * 8 + o;
            pstats[(size_t)c        * 2048 + blk] = s1;
            pstats[(size_t)(32 + c) * 2048 + blk] = s2;
        }
    }
}

// ---------- reduce pstats rows of 2048 -> dst[row] ----------
__global__ __launch_bounds__(256) void k_reduce(const float* __restrict__ src,
                                                float* __restrict__ dst){
    __shared__ float ls[4];
    int row = blockIdx.x, t = threadIdx.x;
    const float* p = src + (size_t)row * 2048 + t;
    float s = 0.f;
    #pragma unroll
    for (int j = 0; j < 8; j++) s += p[j * 256];
    #pragma unroll
    for (int d = 32; d > 0; d >>= 1) s += __shfl_down(s, d);
    if ((t & 63) == 0) ls[t >> 6] = s;
    __syncthreads();
    if (t == 0) dst[row] = ls[0] + ls[1] + ls[2] + ls[3];
}

// ---------- BN finalize (in-block) + apply + PReLU + residual ----------
__global__ __launch_bounds__(256) void k_bnapply(const float* __restrict__ Y,
                                                 const float* __restrict__ stats,
                                                 const float* __restrict__ g,
                                                 const float* __restrict__ be,
                                                 const float* __restrict__ keep_in,
                                                 const float* __restrict__ aptr,
                                                 float* __restrict__ Zout,
                                                 float* __restrict__ keep_out){
    __shared__ float s_sc[32], s_sh[32];
    if (threadIdx.x < 32){
        int c = threadIdx.x;
        const float inv = 1.f / (8.f * PIXv);
        float mu  = stats[c] * inv;
        float var = stats[32 + c] * inv - mu * mu;
        float sc  = g[c] * rsqrtf(var + 1e-5f);
        s_sc[c] = sc;
        s_sh[c] = be[c] - mu * sc;
    }
    __syncthreads();
    const float al = *aptr;
    const size_t tot = (size_t)8 * 32 * PIXv / 4;
    for (size_t i = (size_t)blockIdx.x * 256 + threadIdx.x; i < tot;
         i += (size_t)gridDim.x * 256){
        int c = (int)((i >> 14) & 31);
        float4 y = ((const float4*)Y)[i];
        float sc = s_sc[c], sh = s_sh[c];
        float4 v;
        v.x = sc * y.x + sh; v.y = sc * y.y + sh;
        v.z = sc * y.z + sh; v.w = sc * y.w + sh;
        v.x = v.x >= 0.f ? v.x : al * v.x;
        v.y = v.y >= 0.f ? v.y : al * v.y;
        v.z = v.z >= 0.f ? v.z : al * v.z;
        v.w = v.w >= 0.f ? v.w : al * v.w;
        if (keep_in){
            float4 kz = ((const float4*)keep_in)[i];
            v.x += kz.x; v.y += kz.y; v.z += kz.z; v.w += kz.w;
        }
        ((float4*)Zout)[i] = v;
        if (keep_out) ((float4*)keep_out)[i] = v;
    }
}

// ---------- final 1x1 conv (Wf) + per-wave partial stats ----------
// pfin layout: [2 rows][2048 slots], slot = blk*4 + wid, blk in [0,512).
__global__ __launch_bounds__(256) void k_final(const float* __restrict__ Z,
                                               const float* __restrict__ Wf,
                                               float* __restrict__ T,
                                               float* __restrict__ pfin){
    int b = blockIdx.y;
    size_t base = (size_t)blockIdx.x * 1024 + (size_t)threadIdx.x * 4;
    const float* Z0 = Z + (size_t)b       * 32 * PIXv + base;
    const float* Z1 = Z + (size_t)(b ^ 4) * 32 * PIXv + base;
    float4 acc = make_float4(0.f, 0.f, 0.f, 0.f);
    #pragma unroll 8
    for (int c = 0; c < 32; c++){
        float w0 = Wf[c], w1 = Wf[32 + c];
        float4 x0 = *(const float4*)(Z0 + (size_t)c * PIXv);
        float4 x1 = *(const float4*)(Z1 + (size_t)c * PIXv);
        acc.x += w0 * x0.x + w1 * x1.x;
        acc.y += w0 * x0.y + w1 * x1.y;
        acc.z += w0 * x0.z + w1 * x1.z;
        acc.w += w0 * x0.w + w1 * x1.w;
    }
    *(float4*)(T + (size_t)b * PIXv + base) = acc;
    float a1 = acc.x + acc.y + acc.z + acc.w;
    float a2 = acc.x * acc.x + acc.y * acc.y + acc.z * acc.z + acc.w * acc.w;
    #pragma unroll
    for (int d = 32; d > 0; d >>= 1){
        a1 += __shfl_down(a1, d);
        a2 += __shfl_down(a2, d);
    }
    if ((threadIdx.x & 63) == 0){
        int slot = (blockIdx.y * 64 + blockIdx.x) * 4 + (threadIdx.x >> 6);
        pfin[slot]        = a1;
        pfin[2048 + slot] = a2;
    }
}

// ---------- final BN (in-block) + m0/m1/mm ----------
__global__ __launch_bounds__(256) void k_mm(const float* __restrict__ T,
                                            const float* __restrict__ fstats,
                                            const float* __restrict__ gf,
                                            const float* __restrict__ bf,
                                            float* __restrict__ out,
                                            float* __restrict__ MMb){
    const float inv = 1.f / (8.f * PIXv);
    float mu  = fstats[0] * inv;
    float var = fstats[1] * inv - mu * mu;
    float sc  = gf[0] * rsqrtf(var + 1e-5f);
    float sh  = bf[0] - mu * sc;
    size_t e = ((size_t)blockIdx.x * 256 + threadIdx.x) * 4;    // over 4*PIX
    float4 t0 = *(const float4*)(T + e);
    float4 t1 = *(const float4*)(T + (size_t)4 * PIXv + e);
    float4 m0, m1, mv;
    m0.x = sc * t0.x + sh; m0.y = sc * t0.y + sh; m0.z = sc * t0.z + sh; m0.w = sc * t0.w + sh;
    m1.x = sc * t1.x + sh; m1.y = sc * t1.y + sh; m1.z = sc * t1.z + sh; m1.w = sc * t1.w + sh;
    mv.x = 0.5f * (m0.x + m1.x); mv.y = 0.5f * (m0.y + m1.y);
    mv.z = 0.5f * (m0.z + m1.z); mv.w = 0.5f * (m0.w + m1.w);
    *(float4*)(out + (size_t)4 * PIXv + e) = m0;
    *(float4*)(out + (size_t)8 * PIXv + e) = m1;
    *(float4*)(MMb + e) = mv;
}

// ---------- row softmax stats: one wave per row ----------
__global__ __launch_bounds__(256) void k_rowstats(const float* __restrict__ MMb,
                                                  float* __restrict__ rmax,
                                                  float* __restrict__ rsum){
    int wid = threadIdx.x >> 6, lane = threadIdx.x & 63;
    int r = blockIdx.x * 4 + wid;                    // 0..1023
    const float* p = MMb + (size_t)r * NMv;
    float4 v = *(const float4*)(p + lane * 4);
    float mx = fmaxf(fmaxf(v.x, v.y), fmaxf(v.z, v.w));
    #pragma unroll
    for (int d = 32; d > 0; d >>= 1) mx = fmaxf(mx, __shfl_xor(mx, d));
    float s = expf(v.x - mx) + expf(v.y - mx) + expf(v.z - mx) + expf(v.w - mx);
    #pragma unroll
    for (int d = 32; d > 0; d >>= 1) s += __shfl_xor(s, d);
    if (lane == 0){ rmax[r] = mx; rsum[r] = s; }
}

// ---------- column softmax stats (chunked atomics) ----------
__global__ __launch_bounds__(256) void k_colmax(const float* __restrict__ MMb,
                                                unsigned* __restrict__ ckey){
    int b = blockIdx.y, ch = blockIdx.x, m = threadIdx.x;
    const float* p = MMb + (size_t)b * PIXv + (size_t)ch * 16 * NMv + m;
    float mx = -3.4e38f;
    #pragma unroll
    for (int n = 0; n < 16; n++) mx = fmaxf(mx, p[(size_t)n * NMv]);
    atomicMax(&ckey[b * NMv + m], fkey(mx));
}
__global__ __launch_bounds__(256) void k_colsum(const float* __restrict__ MMb,
                                                const unsigned* __restrict__ ckey,
                                                float* __restrict__ csum){
    int b = blockIdx.y, ch = blockIdx.x, m = threadIdx.x;
    const float* p = MMb + (size_t)b * PIXv + (size_t)ch * 16 * NMv + m;
    float cm = unfkey(ckey[b * NMv + m]);
    float s = 0.f;
    #pragma unroll
    for (int n = 0; n < 16; n++) s += expf(p[(size_t)n * NMv] - cm);
    atomicAdd(&csum[b * NMv + m], s);
}

// ---------- agg = min(row_softmax, col_softmax) ----------
__global__ __launch_bounds__(256) void k_agg(const float* __restrict__ MMb,
                                             const float* __restrict__ rmax,
                                             const float* __restrict__ rsum,
                                             const unsigned* __restrict__ ckey,
                                             const float* __restrict__ csum,
                                             float* __restrict__ out){
    size_t e = ((size_t)blockIdx.x * 256 + threadIdx.x) * 4;
    int r = (int)(e >> 8);
    int b = (int)(e >> 16);
    int m = (int)(e & 255);
    int cb = b * NMv + m;
    float rm = rmax[r], rsi = 1.f / rsum[r];
    float4 v = *(const float4*)(MMb + e);
    float4 o;
    o.x = fminf(expf(v.x - rm) * rsi, expf(v.x - unfkey(ckey[cb + 0])) / csum[cb + 0]);
    o.y = fminf(expf(v.y - rm) * rsi, expf(v.y - unfkey(ckey[cb + 1])) / csum[cb + 1]);
    o.z = fminf(expf(v.z - rm) * rsi, expf(v.z - unfkey(ckey[cb + 2])) / csum[cb + 2]);
    o.w = fminf(expf(v.w - rm) * rsi, expf(v.w - unfkey(ckey[cb + 3])) / csum[cb + 3]);
    *(float4*)(out + e) = o;
}

extern "C" void kernel_launch(void* const* d_in, const int* in_sizes, int n_in,
                              void* d_out, int out_size, void* d_ws, size_t ws_size,
                              hipStream_t stream){
    (void)in_sizes; (void)n_in; (void)out_size; (void)ws_size;
    const float* Za  = (const float*)d_in[0];
    const float* Zb  = (const float*)d_in[1];
    const float* Wm0 = (const float*)d_in[2];
    const float* bm0 = (const float*)d_in[3];
    const float* W0  = (const float*)d_in[4];
    const float* g0  = (const float*)d_in[5];
    const float* be0 = (const float*)d_in[6];
    const float* Wm  = (const float*)d_in[7];
    const float* bm  = (const float*)d_in[8];
    const float* W   = (const float*)d_in[9];
    const float* g   = (const float*)d_in[10];
    const float* be  = (const float*)d_in[11];
    const float* ap  = (const float*)d_in[12];
    const float* Wf  = (const float*)d_in[13];
    const float* gf  = (const float*)d_in[14];
    const float* bf  = (const float*)d_in[15];
    float* out = (float*)d_out;

    size_t off = 0;
    char* wsb = (char*)d_ws;
    auto alloc = [&](size_t bytes) -> void* {
        void* p = wsb + off;
        off += (bytes + 255) & ~(size_t)255;
        return p;
    };
    float*    Zbuf  = (float*)   alloc((size_t)8 * 32 * PIXv * 4);
    float*    Zkeep = (float*)   alloc((size_t)8 * 32 * PIXv * 4);
    float*    Ybuf  = (float*)   alloc((size_t)8 * 32 * PIXv * 4);
    unsigned* zkey  = (unsigned*)alloc((size_t)8 * 64 * NMv * 4);
    float*    zmaxW = (float*)   alloc((size_t)8 * 32 * NMv * 4);
    float*    stats = (float*)   alloc(64 * 4);
    float*    T     = (float*)   alloc((size_t)8 * PIXv * 4);
    float*    fstats= (float*)   alloc(2 * 4);
    float*    MMb   = (float*)   alloc((size_t)4 * PIXv * 4);
    float*    rmaxb = (float*)   alloc(1024 * 4);
    float*    rsumb = (float*)   alloc(1024 * 4);
    unsigned* ckey  = (unsigned*)alloc(1024 * 4);
    float*    csum  = (float*)   alloc(1024 * 4);
    float*    pstats= (float*)   alloc((size_t)64 * 2048 * 4);   // per-block BN partials
    float*    pfin  = (float*)   alloc((size_t)2 * 2048 * 4);    // per-wave final-BN partials

    // Z0
    k_prep<<<dim3(8, 8, 8), dim3(32, 8), 0, stream>>>(Za, Zb, Zbuf);

    for (int i = 0; i < 6; i++){
        const float *Wm_l, *bm_l, *W_l, *g_l, *be_l;
        int C;
        if (i == 0){ Wm_l = Wm0; bm_l = bm0; W_l = W0; g_l = g0; be_l = be0; C = 1; }
        else {
            Wm_l = Wm + (size_t)(i - 1) * 64 * 64;
            bm_l = bm + (size_t)(i - 1) * 64;
            W_l  = W  + (size_t)(i - 1) * 32 * 128;
            g_l  = g  + (size_t)(i - 1) * 32;
            be_l = be + (size_t)(i - 1) * 32;
            C = 32;
        }
        hipMemsetAsync(zkey, 0, (size_t)8 * 64 * NMv * 4, stream);
        if (C == 1) k_zmax<1 ><<<dim3(4, 16, 8), 256, 0, stream>>>(Zbuf, Wm_l, bm_l, zkey);
        else        k_zmax<32><<<dim3(4, 16, 8), 256, 0, stream>>>(Zbuf, Wm_l, bm_l, zkey);
        k_zmaxw<<<dim3(32, 8), 256, 0, stream>>>(zkey, W_l, 2 * C + 64, zmaxW);
        if (C == 1) k_conv<1 ><<<dim3(256, 8), 256, 0, stream>>>(Zbuf, W_l, zmaxW, Ybuf, pstats);
        else        k_conv<32><<<dim3(256, 8), 256, 0, stream>>>(Zbuf, W_l, zmaxW, Ybuf, pstats);
        k_reduce<<<64, 256, 0, stream>>>(pstats, stats);
        bool addk   = (i == 2 || i == 4);
        bool storek = (i % 2 == 0);
        k_bnapply<<<4096, 256, 0, stream>>>(Ybuf, stats, g_l, be_l,
                                            addk ? Zkeep : (const float*)nullptr, ap,
                                            Zbuf, storek ? Zkeep : (float*)nullptr);
    }

    k_final<<<dim3(64, 8), 256, 0, stream>>>(Zbuf, Wf, T, pfin);
    k_reduce<<<2, 256, 0, stream>>>(pfin, fstats);
    k_mm<<<256, 256, 0, stream>>>(T, fstats, gf, bf, out, MMb);
    k_rowstats<<<256, 256, 0, stream>>>(MMb, rmaxb, rsumb);
    hipMemsetAsync(ckey, 0, 1024 * 4, stream);
    hipMemsetAsync(csum, 0, 1024 * 4, stream);
    k_colmax<<<dim3(16, 4), 256, 0, stream>>>(MMb, ckey);
    k_colsum<<<dim3(16, 4), 256, 0, stream>>>(MMb, ckey, csum);
    k_agg<<<256, 256, 0, stream>>>(MMb, rmaxb, rsumb, ckey, csum, out);
}

// Round 8
// 1339.574 us; speedup vs baseline: 4.4885x; 1.0401x over previous
//
#include <hip/hip_runtime.h>

static constexpr int NMv  = 256;
static constexpr int PIXv = 65536;   // 256*256

// ---------- float <-> sortable key (for atomicMax on floats) ----------
__device__ __forceinline__ unsigned fkey(float f){
    unsigned b = __float_as_uint(f);
    return (b & 0x80000000u) ? ~b : (b | 0x80000000u);
}
__device__ __forceinline__ float unfkey(unsigned k){
    unsigned b = (k & 0x80000000u) ? (k & 0x7fffffffu) : ~k;
    return __uint_as_float(b);
}

// ---------- build Z0 = concat([Za, swap(Zb)], 0), shape (8,1,256,256) ----------
__global__ __launch_bounds__(256) void k_prep(const float* __restrict__ Za,
                                              const float* __restrict__ Zb,
                                              float* __restrict__ Z){
    __shared__ float tile[32][33];
    int b  = blockIdx.z;
    int tx = threadIdx.x, ty = threadIdx.y;     // 32 x 8
    int n0 = blockIdx.y * 32, m0 = blockIdx.x * 32;
    if (b < 4){
        const float* src = Za + (size_t)b * PIXv;
        float*       dst = Z  + (size_t)b * PIXv;
        for (int j = 0; j < 32; j += 8){
            int n = n0 + ty + j;
            dst[n * NMv + m0 + tx] = src[n * NMv + m0 + tx];
        }
    } else {
        const float* src = Zb + (size_t)(b - 4) * PIXv;
        for (int j = 0; j < 32; j += 8)
            tile[ty + j][tx] = src[(m0 + ty + j) * NMv + n0 + tx];
        __syncthreads();
        float* dst = Z + (size_t)b * PIXv;
        for (int j = 0; j < 32; j += 8)
            dst[(n0 + ty + j) * NMv + m0 + tx] = tile[tx][ty + j];
    }
}

// ---------- fused z = Wm*X + bm with axis-max reduction, latency-hidden ----------
// grid (4, 32, 8) block 256. m-tile 64 px, n-chunk NCH=8 rows.
// thread: 2 channels (c0, c0+1) x 8 m's (mg*8..+7).
// Register-prefetch double-buffer: next row's global loads issued right after the
// LDS write, so HBM latency hides under the current row's FMAs (2 blocks/CU was
// barrier-stalled ~80% at 157us; see R7 notes).
//  b<4 : max over n -> out (c, m): in-register running max, atomicMax at end.
//  b>=4: max over m -> out (c, n): per-row thread-max + shfl over mg octet, atomicMax per tile.
template<int C>
__global__ __launch_bounds__(256) void k_zmax(const float* __restrict__ Z,
                                              const float* __restrict__ Wm,
                                              const float* __restrict__ bm,
                                              unsigned* __restrict__ zkey){
    constexpr int K2  = 2 * C;
    constexpr int NCH = 8;
    constexpr int NS  = (K2 * 16 + 255) / 256;   // staging float4s per thread (4 for C=32, 1 for C=1)
    __shared__ float Wms[K2 * 64];     // [k][c]
    __shared__ float Xs[K2 * 68];      // [k][64 px + pad4]
    int b = blockIdx.z;
    int t = threadIdx.x;
    for (int i = t; i < 64 * K2; i += 256){
        int c = i / K2, k = i % K2;
        Wms[k * 64 + c] = Wm[i];
    }
    const float* Z0 = Z + (size_t)b       * C * PIXv;
    const float* Z1 = Z + (size_t)(b ^ 4) * C * PIXv;
    int m0 = blockIdx.x * 64, n0 = blockIdx.y * NCH;
    int c0 = (t >> 3) * 2, mg = t & 7;
    float bmv0 = bm[c0], bmv1 = bm[c0 + 1];

    float4 rbuf[NS];
    auto issue = [&](int n){
        #pragma unroll
        for (int j = 0; j < NS; j++){
            int s = t + j * 256;
            if (s < K2 * 16){
                int k = s >> 4, m4 = (s & 15) * 4;
                const float* src = (k < C ? Z0 + (size_t)k * PIXv
                                          : Z1 + (size_t)(k - C) * PIXv) + n * NMv + m0 + m4;
                rbuf[j] = *(const float4*)src;
            }
        }
    };
    issue(n0);

    float mx[2][8];
    #pragma unroll
    for (int a = 0; a < 2; a++)
        #pragma unroll
        for (int j = 0; j < 8; j++) mx[a][j] = -3.4e38f;

    for (int ni = 0; ni < NCH; ni++){
        __syncthreads();                       // previous compute done; LDS free
        #pragma unroll
        for (int j = 0; j < NS; j++){
            int s = t + j * 256;
            if (s < K2 * 16){
                int k = s >> 4, m4 = (s & 15) * 4;
                *(float4*)&Xs[k * 68 + m4] = rbuf[j];
            }
        }
        if (ni + 1 < NCH) issue(n0 + ni + 1);  // prefetch next row under compute
        __syncthreads();                       // Xs visible

        float acc[2][8];
        #pragma unroll
        for (int a = 0; a < 2; a++)
            #pragma unroll
            for (int j = 0; j < 8; j++) acc[a][j] = 0.f;
        #pragma unroll 8
        for (int k = 0; k < K2; k++){
            const float2 w  = *(const float2*)&Wms[k * 64 + c0];
            const float4 x0 = *(const float4*)&Xs[k * 68 + mg * 8];
            const float4 x1 = *(const float4*)&Xs[k * 68 + mg * 8 + 4];
            acc[0][0] += w.x * x0.x; acc[0][1] += w.x * x0.y;
            acc[0][2] += w.x * x0.z; acc[0][3] += w.x * x0.w;
            acc[0][4] += w.x * x1.x; acc[0][5] += w.x * x1.y;
            acc[0][6] += w.x * x1.z; acc[0][7] += w.x * x1.w;
            acc[1][0] += w.y * x0.x; acc[1][1] += w.y * x0.y;
            acc[1][2] += w.y * x0.z; acc[1][3] += w.y * x0.w;
            acc[1][4] += w.y * x1.x; acc[1][5] += w.y * x1.y;
            acc[1][6] += w.y * x1.z; acc[1][7] += w.y * x1.w;
        }

        if (b < 4){
            #pragma unroll
            for (int a = 0; a < 2; a++)
                #pragma unroll
                for (int j = 0; j < 8; j++) mx[a][j] = fmaxf(mx[a][j], acc[a][j]);
        } else {
            int n = n0 + ni;
            #pragma unroll
            for (int a = 0; a < 2; a++){
                float v = fmaxf(fmaxf(fmaxf(acc[a][0], acc[a][1]), fmaxf(acc[a][2], acc[a][3])),
                                fmaxf(fmaxf(acc[a][4], acc[a][5]), fmaxf(acc[a][6], acc[a][7])));
                v = fmaxf(v, __shfl_xor(v, 1));
                v = fmaxf(v, __shfl_xor(v, 2));
                v = fmaxf(v, __shfl_xor(v, 4));
                if (mg == 0)
                    atomicMax(&zkey[((size_t)b * 64 + c0 + a) * NMv + n],
                              fkey(v + (a ? bmv1 : bmv0)));
            }
        }
    }
    if (b < 4){
        #pragma unroll
        for (int a = 0; a < 2; a++){
            float bmv = a ? bmv1 : bmv0;
            #pragma unroll
            for (int j = 0; j < 8; j++)
                atomicMax(&zkey[((size_t)b * 64 + c0 + a) * NMv + m0 + mg * 8 + j],
                          fkey(mx[a][j] + bmv));
        }
    }
}

// ---------- zmaxW[b,oc,p] = sum_c W[oc, 2C+c] * zmax[b,c,p] ----------
__global__ __launch_bounds__(256) void k_zmaxw(const unsigned* __restrict__ zkey,
                                               const float* __restrict__ W, int Wst,
                                               float* __restrict__ zmaxW){
    int oc = blockIdx.x, b = blockIdx.y, p = threadIdx.x;
    const float* wrow = W + (size_t)oc * Wst + (Wst - 64);
    float s = 0.f;
    #pragma unroll 8
    for (int c = 0; c < 64; c++)
        s += wrow[c] * unfkey(zkey[((size_t)b * 64 + c) * NMv + p]);
    zmaxW[((size_t)b * 32 + oc) * NMv + p] = s;
}

// ---------- y = W[:, :2C]*X + zmaxW ; per-block BN partials (NO same-address atomics) ----------
// grid (256 rows, 8 b), block 256. thread: 4 pixels (p4*4..+3) x 8 oc (og*8..+7)
// pstats layout: [64 rows][2048 blocks]; row r<32: sum of channel r, r>=32: sumsq of r-32.
template<int C>
__global__ __launch_bounds__(256) void k_conv(const float* __restrict__ Z,
                                              const float* __restrict__ Wl,
                                              const float* __restrict__ zmaxW,
                                              float* __restrict__ Y,
                                              float* __restrict__ pstats){
    constexpr int K2 = 2 * C;
    constexpr int KC = (K2 < 16) ? K2 : 16;
    __shared__ float Ws[K2 * 32];       // [k][oc]
    __shared__ float Xs[KC * 256];      // [kk][m]
    int b   = blockIdx.y;
    int row = blockIdx.x;
    int t   = threadIdx.x;
    int p4  = t & 63, og = t >> 6;
    for (int i = t; i < K2 * 32; i += 256){
        int k = i >> 5, oc = i & 31;
        Ws[i] = Wl[(size_t)oc * (K2 + 64) + k];
    }
    const float* Z0 = Z + ((size_t)b       * C) * PIXv + (size_t)row * NMv;
    const float* Z1 = Z + ((size_t)(b ^ 4) * C) * PIXv + (size_t)row * NMv;
    float acc[4][8];
    #pragma unroll
    for (int j = 0; j < 4; j++)
        #pragma unroll
        for (int o = 0; o < 8; o++) acc[j][o] = 0.f;

    for (int kc = 0; kc < K2; kc += KC){
        __syncthreads();
        for (int s = t; s < KC * 64; s += 256){
            int k = kc + (s >> 6), m4 = (s & 63) * 4;
            const float* src = (k < C ? Z0 + (size_t)k * PIXv
                                      : Z1 + (size_t)(k - C) * PIXv) + m4;
            *(float4*)&Xs[(s >> 6) * 256 + m4] = *(const float4*)src;
        }
        __syncthreads();
        #pragma unroll 4
        for (int kk = 0; kk < KC; kk++){
            const float4 xv = *(const float4*)&Xs[kk * 256 + p4 * 4];
            const float4 wa = *(const float4*)&Ws[(kc + kk) * 32 + og * 8];
            const float4 wb = *(const float4*)&Ws[(kc + kk) * 32 + og * 8 + 4];
            const float xx[4] = {xv.x, xv.y, xv.z, xv.w};
            const float ww[8] = {wa.x, wa.y, wa.z, wa.w, wb.x, wb.y, wb.z, wb.w};
            #pragma unroll
            for (int j = 0; j < 4; j++)
                #pragma unroll
                for (int o = 0; o < 8; o++)
                    acc[j][o] += xx[j] * ww[o];
        }
    }
    // add max-part contribution
    if (b < 4){
        #pragma unroll
        for (int o = 0; o < 8; o++){
            float4 zw = *(const float4*)&zmaxW[((size_t)b * 32 + og * 8 + o) * NMv + p4 * 4];
            acc[0][o] += zw.x; acc[1][o] += zw.y; acc[2][o] += zw.z; acc[3][o] += zw.w;
        }
    } else {
        #pragma unroll
        for (int o = 0; o < 8; o++){
            float zw = zmaxW[((size_t)b * 32 + og * 8 + o) * NMv + row];
            acc[0][o] += zw; acc[1][o] += zw; acc[2][o] += zw; acc[3][o] += zw;
        }
    }
    // write y
    float* yb = Y + ((size_t)b * 32 + og * 8) * PIXv + (size_t)row * NMv + p4 * 4;
    #pragma unroll
    for (int o = 0; o < 8; o++){
        float4 v = make_float4(acc[0][o], acc[1][o], acc[2][o], acc[3][o]);
        *(float4*)(yb + (size_t)o * PIXv) = v;
    }
    // BN partials: each wave owns channels og*8..og*8+7 exclusively; wave covers the
    // full row (64 lanes * 4 px). lane0 writes the per-block partial -> no contention.
    int blk = b * 256 + row;                  // [0, 2048)
    #pragma unroll
    for (int o = 0; o < 8; o++){
        float s1 = acc[0][o] + acc[1][o] + acc[2][o] + acc[3][o];
        float s2 = acc[0][o] * acc[0][o] + acc[1][o] * acc[1][o] +
                   acc[2][o] * acc[2][o] + acc[3][o] * acc[3][o];
        #pragma unroll
        for (int d = 32; d > 0; d >>= 1){
            s1 += __shfl_down(s1, d);
            s2 += __shfl_down(s2, d);
        }
        if ((t & 63) == 0){
            int c = og * 8 + o;
            pstats[(size_t)c        * 2048 + blk] = s1;
            pstats[(size_t)(32 + c) * 2048 + blk] = s2;
        }
    }
}

// ---------- reduce pstats rows of 2048 -> dst[row] ----------
__global__ __launch_bounds__(256) void k_reduce(const float* __restrict__ src,
                                                float* __restrict__ dst){
    __shared__ float ls[4];
    int row = blockIdx.x, t = threadIdx.x;
    const float* p = src + (size_t)row * 2048 + t;
    float s = 0.f;
    #pragma unroll
    for (int j = 0; j < 8; j++) s += p[j * 256];
    #pragma unroll
    for (int d = 32; d > 0; d >>= 1) s += __shfl_down(s, d);
    if ((t & 63) == 0) ls[t >> 6] = s;
    __syncthreads();
    if (t == 0) dst[row] = ls[0] + ls[1] + ls[2] + ls[3];
}

// ---------- BN finalize (in-block) + apply + PReLU + residual ----------
__global__ __launch_bounds__(256) void k_bnapply(const float* __restrict__ Y,
                                                 const float* __restrict__ stats,
                                                 const float* __restrict__ g,
                                                 const float* __restrict__ be,
                                                 const float* __restrict__ keep_in,
                                                 const float* __restrict__ aptr,
                                                 float* __restrict__ Zout,
                                                 float* __restrict__ keep_out){
    __shared__ float s_sc[32], s_sh[32];
    if (threadIdx.x < 32){
        int c = threadIdx.x;
        const float inv = 1.f / (8.f * PIXv);
        float mu  = stats[c] * inv;
        float var = stats[32 + c] * inv - mu * mu;
        float sc  = g[c] * rsqrtf(var + 1e-5f);
        s_sc[c] = sc;
        s_sh[c] = be[c] - mu * sc;
    }
    __syncthreads();
    const float al = *aptr;
    const size_t tot = (size_t)8 * 32 * PIXv / 4;
    for (size_t i = (size_t)blockIdx.x * 256 + threadIdx.x; i < tot;
         i += (size_t)gridDim.x * 256){
        int c = (int)((i >> 14) & 31);
        float4 y = ((const float4*)Y)[i];
        float sc = s_sc[c], sh = s_sh[c];
        float4 v;
        v.x = sc * y.x + sh; v.y = sc * y.y + sh;
        v.z = sc * y.z + sh; v.w = sc * y.w + sh;
        v.x = v.x >= 0.f ? v.x : al * v.x;
        v.y = v.y >= 0.f ? v.y : al * v.y;
        v.z = v.z >= 0.f ? v.z : al * v.z;
        v.w = v.w >= 0.f ? v.w : al * v.w;
        if (keep_in){
            float4 kz = ((const float4*)keep_in)[i];
            v.x += kz.x; v.y += kz.y; v.z += kz.z; v.w += kz.w;
        }
        ((float4*)Zout)[i] = v;
        if (keep_out) ((float4*)keep_out)[i] = v;
    }
}

// ---------- final 1x1 conv (Wf) + per-wave partial stats ----------
// pfin layout: [2 rows][2048 slots], slot = blk*4 + wid, blk in [0,512).
__global__ __launch_bounds__(256) void k_final(const float* __restrict__ Z,
                                               const float* __restrict__ Wf,
                                               float* __restrict__ T,
                                               float* __restrict__ pfin){
    int b = blockIdx.y;
    size_t base = (size_t)blockIdx.x * 1024 + (size_t)threadIdx.x * 4;
    const float* Z0 = Z + (size_t)b       * 32 * PIXv + base;
    const float* Z1 = Z + (size_t)(b ^ 4) * 32 * PIXv + base;
    float4 acc = make_float4(0.f, 0.f, 0.f, 0.f);
    #pragma unroll 8
    for (int c = 0; c < 32; c++){
        float w0 = Wf[c], w1 = Wf[32 + c];
        float4 x0 = *(const float4*)(Z0 + (size_t)c * PIXv);
        float4 x1 = *(const float4*)(Z1 + (size_t)c * PIXv);
        acc.x += w0 * x0.x + w1 * x1.x;
        acc.y += w0 * x0.y + w1 * x1.y;
        acc.z += w0 * x0.z + w1 * x1.z;
        acc.w += w0 * x0.w + w1 * x1.w;
    }
    *(float4*)(T + (size_t)b * PIXv + base) = acc;
    float a1 = acc.x + acc.y + acc.z + acc.w;
    float a2 = acc.x * acc.x + acc.y * acc.y + acc.z * acc.z + acc.w * acc.w;
    #pragma unroll
    for (int d = 32; d > 0; d >>= 1){
        a1 += __shfl_down(a1, d);
        a2 += __shfl_down(a2, d);
    }
    if ((threadIdx.x & 63) == 0){
        int slot = (blockIdx.y * 64 + blockIdx.x) * 4 + (threadIdx.x >> 6);
        pfin[slot]        = a1;
        pfin[2048 + slot] = a2;
    }
}

// ---------- final BN (in-block) + m0/m1/mm ----------
__global__ __launch_bounds__(256) void k_mm(const float* __restrict__ T,
                                            const float* __restrict__ fstats,
                                            const float* __restrict__ gf,
                                            const float* __restrict__ bf,
                                            float* __restrict__ out,
                                            float* __restrict__ MMb){
    const float inv = 1.f / (8.f * PIXv);
    float mu  = fstats[0] * inv;
    float var = fstats[1] * inv - mu * mu;
    float sc  = gf[0] * rsqrtf(var + 1e-5f);
    float sh  = bf[0] - mu * sc;
    size_t e = ((size_t)blockIdx.x * 256 + threadIdx.x) * 4;    // over 4*PIX
    float4 t0 = *(const float4*)(T + e);
    float4 t1 = *(const float4*)(T + (size_t)4 * PIXv + e);
    float4 m0, m1, mv;
    m0.x = sc * t0.x + sh; m0.y = sc * t0.y + sh; m0.z = sc * t0.z + sh; m0.w = sc * t0.w + sh;
    m1.x = sc * t1.x + sh; m1.y = sc * t1.y + sh; m1.z = sc * t1.z + sh; m1.w = sc * t1.w + sh;
    mv.x = 0.5f * (m0.x + m1.x); mv.y = 0.5f * (m0.y + m1.y);
    mv.z = 0.5f * (m0.z + m1.z); mv.w = 0.5f * (m0.w + m1.w);
    *(float4*)(out + (size_t)4 * PIXv + e) = m0;
    *(float4*)(out + (size_t)8 * PIXv + e) = m1;
    *(float4*)(MMb + e) = mv;
}

// ---------- row softmax stats: one wave per row ----------
__global__ __launch_bounds__(256) void k_rowstats(const float* __restrict__ MMb,
                                                  float* __restrict__ rmax,
                                                  float* __restrict__ rsum){
    int wid = threadIdx.x >> 6, lane = threadIdx.x & 63;
    int r = blockIdx.x * 4 + wid;                    // 0..1023
    const float* p = MMb + (size_t)r * NMv;
    float4 v = *(const float4*)(p + lane * 4);
    float mx = fmaxf(fmaxf(v.x, v.y), fmaxf(v.z, v.w));
    #pragma unroll
    for (int d = 32; d > 0; d >>= 1) mx = fmaxf(mx, __shfl_xor(mx, d));
    float s = expf(v.x - mx) + expf(v.y - mx) + expf(v.z - mx) + expf(v.w - mx);
    #pragma unroll
    for (int d = 32; d > 0; d >>= 1) s += __shfl_xor(s, d);
    if (lane == 0){ rmax[r] = mx; rsum[r] = s; }
}

// ---------- column softmax stats (chunked atomics) ----------
__global__ __launch_bounds__(256) void k_colmax(const float* __restrict__ MMb,
                                                unsigned* __restrict__ ckey){
    int b = blockIdx.y, ch = blockIdx.x, m = threadIdx.x;
    const float* p = MMb + (size_t)b * PIXv + (size_t)ch * 16 * NMv + m;
    float mx = -3.4e38f;
    #pragma unroll
    for (int n = 0; n < 16; n++) mx = fmaxf(mx, p[(size_t)n * NMv]);
    atomicMax(&ckey[b * NMv + m], fkey(mx));
}
__global__ __launch_bounds__(256) void k_colsum(const float* __restrict__ MMb,
                                                const unsigned* __restrict__ ckey,
                                                float* __restrict__ csum){
    int b = blockIdx.y, ch = blockIdx.x, m = threadIdx.x;
    const float* p = MMb + (size_t)b * PIXv + (size_t)ch * 16 * NMv + m;
    float cm = unfkey(ckey[b * NMv + m]);
    float s = 0.f;
    #pragma unroll
    for (int n = 0; n < 16; n++) s += expf(p[(size_t)n * NMv] - cm);
    atomicAdd(&csum[b * NMv + m], s);
}

// ---------- agg = min(row_softmax, col_softmax) ----------
__global__ __launch_bounds__(256) void k_agg(const float* __restrict__ MMb,
                                             const float* __restrict__ rmax,
                                             const float* __restrict__ rsum,
                                             const unsigned* __restrict__ ckey,
                                             const float* __restrict__ csum,
                                             float* __restrict__ out){
    size_t e = ((size_t)blockIdx.x * 256 + threadIdx.x) * 4;
    int r = (int)(e >> 8);
    int b = (int)(e >> 16);
    int m = (int)(e & 255);
    int cb = b * NMv + m;
    float rm = rmax[r], rsi = 1.f / rsum[r];
    float4 v = *(const float4*)(MMb + e);
    float4 o;
    o.x = fminf(expf(v.x - rm) * rsi, expf(v.x - unfkey(ckey[cb + 0])) / csum[cb + 0]);
    o.y = fminf(expf(v.y - rm) * rsi, expf(v.y - unfkey(ckey[cb + 1])) / csum[cb + 1]);
    o.z = fminf(expf(v.z - rm) * rsi, expf(v.z - unfkey(ckey[cb + 2])) / csum[cb + 2]);
    o.w = fminf(expf(v.w - rm) * rsi, expf(v.w - unfkey(ckey[cb + 3])) / csum[cb + 3]);
    *(float4*)(out + e) = o;
}

extern "C" void kernel_launch(void* const* d_in, const int* in_sizes, int n_in,
                              void* d_out, int out_size, void* d_ws, size_t ws_size,
                              hipStream_t stream){
    (void)in_sizes; (void)n_in; (void)out_size; (void)ws_size;
    const float* Za  = (const float*)d_in[0];
    const float* Zb  = (const float*)d_in[1];
    const float* Wm0 = (const float*)d_in[2];
    const float* bm0 = (const float*)d_in[3];
    const float* W0  = (const float*)d_in[4];
    const float* g0  = (const float*)d_in[5];
    const float* be0 = (const float*)d_in[6];
    const float* Wm  = (const float*)d_in[7];
    const float* bm  = (const float*)d_in[8];
    const float* W   = (const float*)d_in[9];
    const float* g   = (const float*)d_in[10];
    const float* be  = (const float*)d_in[11];
    const float* ap  = (const float*)d_in[12];
    const float* Wf  = (const float*)d_in[13];
    const float* gf  = (const float*)d_in[14];
    const float* bf  = (const float*)d_in[15];
    float* out = (float*)d_out;

    size_t off = 0;
    char* wsb = (char*)d_ws;
    auto alloc = [&](size_t bytes) -> void* {
        void* p = wsb + off;
        off += (bytes + 255) & ~(size_t)255;
        return p;
    };
    float*    Zbuf  = (float*)   alloc((size_t)8 * 32 * PIXv * 4);
    float*    Zkeep = (float*)   alloc((size_t)8 * 32 * PIXv * 4);
    float*    Ybuf  = (float*)   alloc((size_t)8 * 32 * PIXv * 4);
    unsigned* zkey  = (unsigned*)alloc((size_t)8 * 64 * NMv * 4);
    float*    zmaxW = (float*)   alloc((size_t)8 * 32 * NMv * 4);
    float*    stats = (float*)   alloc(64 * 4);
    float*    T     = (float*)   alloc((size_t)8 * PIXv * 4);
    float*    fstats= (float*)   alloc(2 * 4);
    float*    MMb   = (float*)   alloc((size_t)4 * PIXv * 4);
    float*    rmaxb = (float*)   alloc(1024 * 4);
    float*    rsumb = (float*)   alloc(1024 * 4);
    unsigned* ckey  = (unsigned*)alloc(1024 * 4);
    float*    csum  = (float*)   alloc(1024 * 4);
    float*    pstats= (float*)   alloc((size_t)64 * 2048 * 4);   // per-block BN partials
    float*    pfin  = (float*)   alloc((size_t)2 * 2048 * 4);    // per-wave final-BN partials

    // Z0
    k_prep<<<dim3(8, 8, 8), dim3(32, 8), 0, stream>>>(Za, Zb, Zbuf);

    for (int i = 0; i < 6; i++){
        const float *Wm_l, *bm_l, *W_l, *g_l, *be_l;
        int C;
        if (i == 0){ Wm_l = Wm0; bm_l = bm0; W_l = W0; g_l = g0; be_l = be0; C = 1; }
        else {
            Wm_l = Wm + (size_t)(i - 1) * 64 * 64;
            bm_l = bm + (size_t)(i - 1) * 64;
            W_l  = W  + (size_t)(i - 1) * 32 * 128;
            g_l  = g  + (size_t)(i - 1) * 32;
            be_l = be + (size_t)(i - 1) * 32;
            C = 32;
        }
        hipMemsetAsync(zkey, 0, (size_t)8 * 64 * NMv * 4, stream);
        if (C == 1) k_zmax<1 ><<<dim3(4, 32, 8), 256, 0, stream>>>(Zbuf, Wm_l, bm_l, zkey);
        else        k_zmax<32><<<dim3(4, 32, 8), 256, 0, stream>>>(Zbuf, Wm_l, bm_l, zkey);
        k_zmaxw<<<dim3(32, 8), 256, 0, stream>>>(zkey, W_l, 2 * C + 64, zmaxW);
        if (C == 1) k_conv<1 ><<<dim3(256, 8), 256, 0, stream>>>(Zbuf, W_l, zmaxW, Ybuf, pstats);
        else        k_conv<32><<<dim3(256, 8), 256, 0, stream>>>(Zbuf, W_l, zmaxW, Ybuf, pstats);
        k_reduce<<<64, 256, 0, stream>>>(pstats, stats);
        bool addk   = (i == 2 || i == 4);
        bool storek = (i % 2 == 0);
        k_bnapply<<<4096, 256, 0, stream>>>(Ybuf, stats, g_l, be_l,
                                            addk ? Zkeep : (const float*)nullptr, ap,
                                            Zbuf, storek ? Zkeep : (float*)nullptr);
    }

    k_final<<<dim3(64, 8), 256, 0, stream>>>(Zbuf, Wf, T, pfin);
    k_reduce<<<2, 256, 0, stream>>>(pfin, fstats);
    k_mm<<<256, 256, 0, stream>>>(T, fstats, gf, bf, out, MMb);
    k_rowstats<<<256, 256, 0, stream>>>(MMb, rmaxb, rsumb);
    hipMemsetAsync(ckey, 0, 1024 * 4, stream);
    hipMemsetAsync(csum, 0, 1024 * 4, stream);
    k_colmax<<<dim3(16, 4), 256, 0, stream>>>(MMb, ckey);
    k_colsum<<<dim3(16, 4), 256, 0, stream>>>(MMb, ckey, csum);
    k_agg<<<256, 256, 0, stream>>>(MMb, rmaxb, rsumb, ckey, csum, out);
}

// Round 10
// 1161.792 us; speedup vs baseline: 5.1753x; 1.1530x over previous
//
#include <hip/hip_runtime.h>

static constexpr int NMv  = 256;
static constexpr int PIXv = 65536;   // 256*256

// ---------- float <-> sortable key (for atomicMax on floats; softmax col stats only) ----------
__device__ __forceinline__ unsigned fkey(float f){
    unsigned b = __float_as_uint(f);
    return (b & 0x80000000u) ? ~b : (b | 0x80000000u);
}
__device__ __forceinline__ float unfkey(unsigned k){
    unsigned b = (k & 0x80000000u) ? (k & 0x7fffffffu) : ~k;
    return __uint_as_float(b);
}

// ---------- build Z0 = concat([Za, swap(Zb)], 0), shape (8,1,256,256) ----------
__global__ __launch_bounds__(256) void k_prep(const float* __restrict__ Za,
                                              const float* __restrict__ Zb,
                                              float* __restrict__ Z){
    __shared__ float tile[32][33];
    int b  = blockIdx.z;
    int tx = threadIdx.x, ty = threadIdx.y;     // 32 x 8
    int n0 = blockIdx.y * 32, m0 = blockIdx.x * 32;
    if (b < 4){
        const float* src = Za + (size_t)b * PIXv;
        float*       dst = Z  + (size_t)b * PIXv;
        for (int j = 0; j < 32; j += 8){
            int n = n0 + ty + j;
            dst[n * NMv + m0 + tx] = src[n * NMv + m0 + tx];
        }
    } else {
        const float* src = Zb + (size_t)(b - 4) * PIXv;
        for (int j = 0; j < 32; j += 8)
            tile[ty + j][tx] = src[(m0 + ty + j) * NMv + n0 + tx];
        __syncthreads();
        float* dst = Z + (size_t)b * PIXv;
        for (int j = 0; j < 32; j += 8)
            dst[(n0 + ty + j) * NMv + m0 + tx] = tile[tx][ty + j];
    }
}

// ---------- fused z = Wm*X with axis-max -> per-block partial maxes (NO atomics) ----------
// grid (4 mt, 32 nchunk, 8 b), block 256 = 2 rows x 128 threads (16 cgrp x 8 mg).
// thread: 4 out-channels (c0..c0+3) x 8 px (mg*8..+7).  NITER=4 row-pairs per block.
// 1-deep register prefetch: next pair's loads issued under current pair's 4Kcy compute.
// b<4 : running max over rows -> pzA[b][chunk=by*2+row_sel][c][m]  (bias folded in k_zred)
// b>=4: per-row max over px  -> pzB[b-4][c][n][mtile4]
template<int C>
__global__ __launch_bounds__(256) void k_zmax(const float* __restrict__ Z,
                                              const float* __restrict__ Wm,
                                              float* __restrict__ pzA,
                                              float* __restrict__ pzB){
    constexpr int K2    = 2 * C;
    constexpr int NITER = 4;
    constexpr int PRS   = K2 * 16;          // float4 slots per row (1024 / 32)
    constexpr int SLOTS = 2 * PRS;          // per pair
    constexpr int NS    = (SLOTS + 255) / 256;
    __shared__ float Wms[K2 * 64];          // [k][c]
    __shared__ float Xs[2 * K2 * 68];       // [row][k][64 px + pad4]
    int b = blockIdx.z;
    int t = threadIdx.x;
    for (int i = t; i < 64 * K2; i += 256){
        int c = i / K2, k = i % K2;
        Wms[k * 64 + c] = Wm[i];
    }
    const float* Z0 = Z + (size_t)b       * C * PIXv;
    const float* Z1 = Z + (size_t)(b ^ 4) * C * PIXv;
    int m0 = blockIdx.x * 64, n0 = blockIdx.y * (2 * NITER);
    int row_sel = t >> 7, tid = t & 127;
    int c0 = (tid >> 3) * 4, mg = tid & 7;

    float4 rbuf[NS];
    auto issue = [&](int base){             // load rows n0+base, n0+base+1
        #pragma unroll
        for (int j = 0; j < NS; j++){
            int s = t + j * 256;
            if (s < SLOTS){
                int row = s / PRS, r = s % PRS, k = r >> 4, m4 = r & 15;
                const float* src = (k < C ? Z0 + (size_t)k * PIXv
                                          : Z1 + (size_t)(k - C) * PIXv)
                                   + (n0 + base + row) * NMv + m0 + m4 * 4;
                rbuf[j] = *(const float4*)src;
            }
        }
    };
    issue(0);

    float mx[4][8];
    #pragma unroll
    for (int a = 0; a < 4; a++)
        #pragma unroll
        for (int j = 0; j < 8; j++) mx[a][j] = -3.4e38f;

    for (int it = 0; it < NITER; ++it){
        __syncthreads();                    // prev compute done; Xs free
        #pragma unroll
        for (int j = 0; j < NS; j++){
            int s = t + j * 256;
            if (s < SLOTS){
                int row = s / PRS, r = s % PRS, k = r >> 4, m4 = r & 15;
                *(float4*)&Xs[row * (K2 * 68) + k * 68 + m4 * 4] = rbuf[j];
            }
        }
        if (it + 1 < NITER) issue(2 * (it + 1));   // prefetch under compute
        __syncthreads();                    // Xs visible

        float acc[4][8];
        #pragma unroll
        for (int a = 0; a < 4; a++)
            #pragma unroll
            for (int j = 0; j < 8; j++) acc[a][j] = 0.f;
        const float* Xr = &Xs[row_sel * (K2 * 68)];
        #pragma unroll 8
        for (int k = 0; k < K2; k++){
            const float4 w  = *(const float4*)&Wms[k * 64 + c0];
            const float4 x0 = *(const float4*)&Xr[k * 68 + mg * 8];
            const float4 x1 = *(const float4*)&Xr[k * 68 + mg * 8 + 4];
            const float wv[4] = {w.x, w.y, w.z, w.w};
            const float xv[8] = {x0.x, x0.y, x0.z, x0.w, x1.x, x1.y, x1.z, x1.w};
            #pragma unroll
            for (int a = 0; a < 4; a++)
                #pragma unroll
                for (int j = 0; j < 8; j++)
                    acc[a][j] += wv[a] * xv[j];
        }

        if (b < 4){
            #pragma unroll
            for (int a = 0; a < 4; a++)
                #pragma unroll
                for (int j = 0; j < 8; j++) mx[a][j] = fmaxf(mx[a][j], acc[a][j]);
        } else {
            int n = n0 + 2 * it + row_sel;
            #pragma unroll
            for (int a = 0; a < 4; a++){
                float v = fmaxf(fmaxf(fmaxf(acc[a][0], acc[a][1]), fmaxf(acc[a][2], acc[a][3])),
                                fmaxf(fmaxf(acc[a][4], acc[a][5]), fmaxf(acc[a][6], acc[a][7])));
                v = fmaxf(v, __shfl_xor(v, 1));
                v = fmaxf(v, __shfl_xor(v, 2));
                v = fmaxf(v, __shfl_xor(v, 4));
                if (mg == 0)
                    pzB[(((size_t)(b - 4) * 64 + c0 + a) * NMv + n) * 4 + blockIdx.x] = v;
            }
        }
    }
    if (b < 4){
        int ch2 = blockIdx.y * 2 + row_sel;           // 64 chunks
        #pragma unroll
        for (int a = 0; a < 4; a++){
            float* dst = &pzA[(((size_t)b * 64 + ch2) * 64 + c0 + a) * NMv + m0 + mg * 8];
            *(float4*)dst       = make_float4(mx[a][0], mx[a][1], mx[a][2], mx[a][3]);
            *(float4*)(dst + 4) = make_float4(mx[a][4], mx[a][5], mx[a][6], mx[a][7]);
        }
    }
}

// ---------- reduce partial maxes -> zmaxf[b][c][p] = max + bm[c] ----------
__global__ __launch_bounds__(256) void k_zred(const float* __restrict__ pzA,
                                              const float* __restrict__ pzB,
                                              const float* __restrict__ bm,
                                              float* __restrict__ zmaxf){
    int c = blockIdx.x, b = blockIdx.y, p = threadIdx.x;
    float v;
    if (b < 4){
        v = -3.4e38f;
        const float* src = pzA + ((size_t)b * 64 * 64 + c) * NMv + p;
        #pragma unroll 8
        for (int j = 0; j < 64; j++)
            v = fmaxf(v, src[(size_t)j * 64 * NMv]);
    } else {
        const float4 q = *(const float4*)&pzB[(((size_t)(b - 4) * 64 + c) * NMv + p) * 4];
        v = fmaxf(fmaxf(q.x, q.y), fmaxf(q.z, q.w));
    }
    zmaxf[((size_t)b * 64 + c) * NMv + p] = v + bm[c];
}

// ---------- zmaxW[b,oc,p] = sum_c W[oc, 2C+c] * zmaxf[b,c,p] ----------
__global__ __launch_bounds__(256) void k_zmaxw(const float* __restrict__ zmaxf,
                                               const float* __restrict__ W, int Wst,
                                               float* __restrict__ zmaxW){
    int oc = blockIdx.x, b = blockIdx.y, p = threadIdx.x;
    const float* wrow = W + (size_t)oc * Wst + (Wst - 64);
    float s = 0.f;
    #pragma unroll 8
    for (int c = 0; c < 64; c++)
        s += wrow[c] * zmaxf[((size_t)b * 64 + c) * NMv + p];
    zmaxW[((size_t)b * 32 + oc) * NMv + p] = s;
}

// ---------- y = W[:, :2C]*X + zmaxW ; per-block BN partials (NO same-address atomics) ----------
template<int C>
__global__ __launch_bounds__(256) void k_conv(const float* __restrict__ Z,
                                              const float* __restrict__ Wl,
                                              const float* __restrict__ zmaxW,
                                              float* __restrict__ Y,
                                              float* __restrict__ pstats){
    constexpr int K2 = 2 * C;
    constexpr int KC = (K2 < 16) ? K2 : 16;
    __shared__ float Ws[K2 * 32];       // [k][oc]
    __shared__ float Xs[KC * 256];      // [kk][m]
    int b   = blockIdx.y;
    int row = blockIdx.x;
    int t   = threadIdx.x;
    int p4  = t & 63, og = t >> 6;
    for (int i = t; i < K2 * 32; i += 256){
        int k = i >> 5, oc = i & 31;
        Ws[i] = Wl[(size_t)oc * (K2 + 64) + k];
    }
    const float* Z0 = Z + ((size_t)b       * C) * PIXv + (size_t)row * NMv;
    const float* Z1 = Z + ((size_t)(b ^ 4) * C) * PIXv + (size_t)row * NMv;
    float acc[4][8];
    #pragma unroll
    for (int j = 0; j < 4; j++)
        #pragma unroll
        for (int o = 0; o < 8; o++) acc[j][o] = 0.f;

    for (int kc = 0; kc < K2; kc += KC){
        __syncthreads();
        for (int s = t; s < KC * 64; s += 256){
            int k = kc + (s >> 6), m4 = (s & 63) * 4;
            const float* src = (k < C ? Z0 + (size_t)k * PIXv
                                      : Z1 + (size_t)(k - C) * PIXv) + m4;
            *(float4*)&Xs[(s >> 6) * 256 + m4] = *(const float4*)src;
        }
        __syncthreads();
        #pragma unroll 4
        for (int kk = 0; kk < KC; kk++){
            const float4 xv = *(const float4*)&Xs[kk * 256 + p4 * 4];
            const float4 wa = *(const float4*)&Ws[(kc + kk) * 32 + og * 8];
            const float4 wb = *(const float4*)&Ws[(kc + kk) * 32 + og * 8 + 4];
            const float xx[4] = {xv.x, xv.y, xv.z, xv.w};
            const float ww[8] = {wa.x, wa.y, wa.z, wa.w, wb.x, wb.y, wb.z, wb.w};
            #pragma unroll
            for (int j = 0; j < 4; j++)
                #pragma unroll
                for (int o = 0; o < 8; o++)
                    acc[j][o] += xx[j] * ww[o];
        }
    }
    if (b < 4){
        #pragma unroll
        for (int o = 0; o < 8; o++){
            float4 zw = *(const float4*)&zmaxW[((size_t)b * 32 + og * 8 + o) * NMv + p4 * 4];
            acc[0][o] += zw.x; acc[1][o] += zw.y; acc[2][o] += zw.z; acc[3][o] += zw.w;
        }
    } else {
        #pragma unroll
        for (int o = 0; o < 8; o++){
            float zw = zmaxW[((size_t)b * 32 + og * 8 + o) * NMv + row];
            acc[0][o] += zw; acc[1][o] += zw; acc[2][o] += zw; acc[3][o] += zw;
        }
    }
    float* yb = Y + ((size_t)b * 32 + og * 8) * PIXv + (size_t)row * NMv + p4 * 4;
    #pragma unroll
    for (int o = 0; o < 8; o++){
        float4 v = make_float4(acc[0][o], acc[1][o], acc[2][o], acc[3][o]);
        *(float4*)(yb + (size_t)o * PIXv) = v;
    }
    int blk = b * 256 + row;                  // [0, 2048)
    #pragma unroll
    for (int o = 0; o < 8; o++){
        float s1 = acc[0][o] + acc[1][o] + acc[2][o] + acc[3][o];
        float s2 = acc[0][o] * acc[0][o] + acc[1][o] * acc[1][o] +
                   acc[2][o] * acc[2][o] + acc[3][o] * acc[3][o];
        #pragma unroll
        for (int d = 32; d > 0; d >>= 1){
            s1 += __shfl_down(s1, d);
            s2 += __shfl_down(s2, d);
        }
        if ((t & 63) == 0){
            int c = og * 8 + o;
            pstats[(size_t)c        * 2048 + blk] = s1;
            pstats[(size_t)(32 + c) * 2048 + blk] = s2;
        }
    }
}

// ---------- reduce pstats rows of 2048 -> dst[row] ----------
__global__ __launch_bounds__(256) void k_reduce(const float* __restrict__ src,
                                                float* __restrict__ dst){
    __shared__ float ls[4];
    int row = blockIdx.x, t = threadIdx.x;
    const float* p = src + (size_t)row * 2048 + t;
    float s = 0.f;
    #pragma unroll
    for (int j = 0; j < 8; j++) s += p[j * 256];
    #pragma unroll
    for (int d = 32; d > 0; d >>= 1) s += __shfl_down(s, d);
    if ((t & 63) == 0) ls[t >> 6] = s;
    __syncthreads();
    if (t == 0) dst[row] = ls[0] + ls[1] + ls[2] + ls[3];
}

// ---------- BN finalize (in-block) + apply + PReLU + residual ----------
__global__ __launch_bounds__(256) void k_bnapply(const float* __restrict__ Y,
                                                 const float* __restrict__ stats,
                                                 const float* __restrict__ g,
                                                 const float* __restrict__ be,
                                                 const float* __restrict__ keep_in,
                                                 const float* __restrict__ aptr,
                                                 float* __restrict__ Zout,
                                                 float* __restrict__ keep_out){
    __shared__ float s_sc[32], s_sh[32];
    if (threadIdx.x < 32){
        int c = threadIdx.x;
        const float inv = 1.f / (8.f * PIXv);
        float mu  = stats[c] * inv;
        float var = stats[32 + c] * inv - mu * mu;
        float sc  = g[c] * rsqrtf(var + 1e-5f);
        s_sc[c] = sc;
        s_sh[c] = be[c] - mu * sc;
    }
    __syncthreads();
    const float al = *aptr;
    const size_t tot = (size_t)8 * 32 * PIXv / 4;
    for (size_t i = (size_t)blockIdx.x * 256 + threadIdx.x; i < tot;
         i += (size_t)gridDim.x * 256){
        int c = (int)((i >> 14) & 31);
        float4 y = ((const float4*)Y)[i];
        float sc = s_sc[c], sh = s_sh[c];
        float4 v;
        v.x = sc * y.x + sh; v.y = sc * y.y + sh;
        v.z = sc * y.z + sh; v.w = sc * y.w + sh;
        v.x = v.x >= 0.f ? v.x : al * v.x;
        v.y = v.y >= 0.f ? v.y : al * v.y;
        v.z = v.z >= 0.f ? v.z : al * v.z;
        v.w = v.w >= 0.f ? v.w : al * v.w;
        if (keep_in){
            float4 kz = ((const float4*)keep_in)[i];
            v.x += kz.x; v.y += kz.y; v.z += kz.z; v.w += kz.w;
        }
        ((float4*)Zout)[i] = v;
        if (keep_out) ((float4*)keep_out)[i] = v;
    }
}

// ---------- final 1x1 conv (Wf) + per-wave partial stats ----------
__global__ __launch_bounds__(256) void k_final(const float* __restrict__ Z,
                                               const float* __restrict__ Wf,
                                               float* __restrict__ T,
                                               float* __restrict__ pfin){
    int b = blockIdx.y;
    size_t base = (size_t)blockIdx.x * 1024 + (size_t)threadIdx.x * 4;
    const float* Z0 = Z + (size_t)b       * 32 * PIXv + base;
    const float* Z1 = Z + (size_t)(b ^ 4) * 32 * PIXv + base;
    float4 acc = make_float4(0.f, 0.f, 0.f, 0.f);
    #pragma unroll 8
    for (int c = 0; c < 32; c++){
        float w0 = Wf[c], w1 = Wf[32 + c];
        float4 x0 = *(const float4*)(Z0 + (size_t)c * PIXv);
        float4 x1 = *(const float4*)(Z1 + (size_t)c * PIXv);
        acc.x += w0 * x0.x + w1 * x1.x;
        acc.y += w0 * x0.y + w1 * x1.y;
        acc.z += w0 * x0.z + w1 * x1.z;
        acc.w += w0 * x0.w + w1 * x1.w;
    }
    *(float4*)(T + (size_t)b * PIXv + base) = acc;
    float a1 = acc.x + acc.y + acc.z + acc.w;
    float a2 = acc.x * acc.x + acc.y * acc.y + acc.z * acc.z + acc.w * acc.w;
    #pragma unroll
    for (int d = 32; d > 0; d >>= 1){
        a1 += __shfl_down(a1, d);
        a2 += __shfl_down(a2, d);
    }
    if ((threadIdx.x & 63) == 0){
        int slot = (blockIdx.y * 64 + blockIdx.x) * 4 + (threadIdx.x >> 6);
        pfin[slot]        = a1;
        pfin[2048 + slot] = a2;
    }
}

// ---------- final BN (in-block) + m0/m1/mm ----------
__global__ __launch_bounds__(256) void k_mm(const float* __restrict__ T,
                                            const float* __restrict__ fstats,
                                            const float* __restrict__ gf,
                                            const float* __restrict__ bf,
                                            float* __restrict__ out,
                                            float* __restrict__ MMb){
    const float inv = 1.f / (8.f * PIXv);
    float mu  = fstats[0] * inv;
    float var = fstats[1] * inv - mu * mu;
    float sc  = gf[0] * rsqrtf(var + 1e-5f);
    float sh  = bf[0] - mu * sc;
    size_t e = ((size_t)blockIdx.x * 256 + threadIdx.x) * 4;    // over 4*PIX
    float4 t0 = *(const float4*)(T + e);
    float4 t1 = *(const float4*)(T + (size_t)4 * PIXv + e);
    float4 m0, m1, mv;
    m0.x = sc * t0.x + sh; m0.y = sc * t0.y + sh; m0.z = sc * t0.z + sh; m0.w = sc * t0.w + sh;
    m1.x = sc * t1.x + sh; m1.y = sc * t1.y + sh; m1.z = sc * t1.z + sh; m1.w = sc * t1.w + sh;
    mv.x = 0.5f * (m0.x + m1.x); mv.y = 0.5f * (m0.y + m1.y);
    mv.z = 0.5f * (m0.z + m1.z); mv.w = 0.5f * (m0.w + m1.w);
    *(float4*)(out + (size_t)4 * PIXv + e) = m0;
    *(float4*)(out + (size_t)8 * PIXv + e) = m1;
    *(float4*)(MMb + e) = mv;
}

// ---------- row softmax stats: one wave per row ----------
__global__ __launch_bounds__(256) void k_rowstats(const float* __restrict__ MMb,
                                                  float* __restrict__ rmax,
                                                  float* __restrict__ rsum){
    int wid = threadIdx.x >> 6, lane = threadIdx.x & 63;
    int r = blockIdx.x * 4 + wid;                    // 0..1023
    const float* p = MMb + (size_t)r * NMv;
    float4 v = *(const float4*)(p + lane * 4);
    float mx = fmaxf(fmaxf(v.x, v.y), fmaxf(v.z, v.w));
    #pragma unroll
    for (int d = 32; d > 0; d >>= 1) mx = fmaxf(mx, __shfl_xor(mx, d));
    float s = expf(v.x - mx) + expf(v.y - mx) + expf(v.z - mx) + expf(v.w - mx);
    #pragma unroll
    for (int d = 32; d > 0; d >>= 1) s += __shfl_xor(s, d);
    if (lane == 0){ rmax[r] = mx; rsum[r] = s; }
}

// ---------- column softmax stats (chunked atomics) ----------
__global__ __launch_bounds__(256) void k_colmax(const float* __restrict__ MMb,
                                                unsigned* __restrict__ ckey){
    int b = blockIdx.y, ch = blockIdx.x, m = threadIdx.x;
    const float* p = MMb + (size_t)b * PIXv + (size_t)ch * 16 * NMv + m;
    float mx = -3.4e38f;
    #pragma unroll
    for (int n = 0; n < 16; n++) mx = fmaxf(mx, p[(size_t)n * NMv]);
    atomicMax(&ckey[b * NMv + m], fkey(mx));
}
__global__ __launch_bounds__(256) void k_colsum(const float* __restrict__ MMb,
                                                const unsigned* __restrict__ ckey,
                                                float* __restrict__ csum){
    int b = blockIdx.y, ch = blockIdx.x, m = threadIdx.x;
    const float* p = MMb + (size_t)b * PIXv + (size_t)ch * 16 * NMv + m;
    float cm = unfkey(ckey[b * NMv + m]);
    float s = 0.f;
    #pragma unroll
    for (int n = 0; n < 16; n++) s += expf(p[(size_t)n * NMv] - cm);
    atomicAdd(&csum[b * NMv + m], s);
}

// ---------- agg = min(row_softmax, col_softmax) ----------
__global__ __launch_bounds__(256) void k_agg(const float* __restrict__ MMb,
                                             const float* __restrict__ rmax,
                                             const float* __restrict__ rsum,
                                             const unsigned* __restrict__ ckey,
                                             const float* __restrict__ csum,
                                             float* __restrict__ out){
    size_t e = ((size_t)blockIdx.x * 256 + threadIdx.x) * 4;
    int r = (int)(e >> 8);
    int b = (int)(e >> 16);
    int m = (int)(e & 255);
    int cb = b * NMv + m;
    float rm = rmax[r], rsi = 1.f / rsum[r];
    float4 v = *(const float4*)(MMb + e);
    float4 o;
    o.x = fminf(expf(v.x - rm) * rsi, expf(v.x - unfkey(ckey[cb + 0])) / csum[cb + 0]);
    o.y = fminf(expf(v.y - rm) * rsi, expf(v.y - unfkey(ckey[cb + 1])) / csum[cb + 1]);
    o.z = fminf(expf(v.z - rm) * rsi, expf(v.z - unfkey(ckey[cb + 2])) / csum[cb + 2]);
    o.w = fminf(expf(v.w - rm) * rsi, expf(v.w - unfkey(ckey[cb + 3])) / csum[cb + 3]);
    *(float4*)(out + e) = o;
}

extern "C" void kernel_launch(void* const* d_in, const int* in_sizes, int n_in,
                              void* d_out, int out_size, void* d_ws, size_t ws_size,
                              hipStream_t stream){
    (void)in_sizes; (void)n_in; (void)out_size; (void)ws_size;
    const float* Za  = (const float*)d_in[0];
    const float* Zb  = (const float*)d_in[1];
    const float* Wm0 = (const float*)d_in[2];
    const float* bm0 = (const float*)d_in[3];
    const float* W0  = (const float*)d_in[4];
    const float* g0  = (const float*)d_in[5];
    const float* be0 = (const float*)d_in[6];
    const float* Wm  = (const float*)d_in[7];
    const float* bm  = (const float*)d_in[8];
    const float* W   = (const float*)d_in[9];
    const float* g   = (const float*)d_in[10];
    const float* be  = (const float*)d_in[11];
    const float* ap  = (const float*)d_in[12];
    const float* Wf  = (const float*)d_in[13];
    const float* gf  = (const float*)d_in[14];
    const float* bf  = (const float*)d_in[15];
    float* out = (float*)d_out;

    size_t off = 0;
    char* wsb = (char*)d_ws;
    auto alloc = [&](size_t bytes) -> void* {
        void* p = wsb + off;
        off += (bytes + 255) & ~(size_t)255;
        return p;
    };
    float*    Zbuf  = (float*)   alloc((size_t)8 * 32 * PIXv * 4);
    float*    Zkeep = (float*)   alloc((size_t)8 * 32 * PIXv * 4);
    float*    Ybuf  = (float*)   alloc((size_t)8 * 32 * PIXv * 4);
    float*    zmaxf = (float*)   alloc((size_t)8 * 64 * NMv * 4);
    float*    zmaxW = (float*)   alloc((size_t)8 * 32 * NMv * 4);
    float*    stats = (float*)   alloc(64 * 4);
    float*    T     = (float*)   alloc((size_t)8 * PIXv * 4);
    float*    fstats= (float*)   alloc(2 * 4);
    float*    MMb   = (float*)   alloc((size_t)4 * PIXv * 4);
    float*    rmaxb = (float*)   alloc(1024 * 4);
    float*    rsumb = (float*)   alloc(1024 * 4);
    unsigned* ckey  = (unsigned*)alloc(1024 * 4);
    float*    csum  = (float*)   alloc(1024 * 4);
    float*    pstats= (float*)   alloc((size_t)64 * 2048 * 4);   // per-block BN partials
    float*    pfin  = (float*)   alloc((size_t)2 * 2048 * 4);    // per-wave final-BN partials

    // zmax partials alias Ybuf (dead between bnapply and next conv):
    // pzA = 4*64*64*256 floats (16 MB), pzB = 4*64*256*4 floats (1 MB) -> 4.45M floats << Ybuf's 16.7M
    float* pzA = Ybuf;
    float* pzB = Ybuf + (size_t)4 * 64 * 64 * NMv;

    // Z0
    k_prep<<<dim3(8, 8, 8), dim3(32, 8), 0, stream>>>(Za, Zb, Zbuf);

    for (int i = 0; i < 6; i++){
        const float *Wm_l, *bm_l, *W_l, *g_l, *be_l;
        int C;
        if (i == 0){ Wm_l = Wm0; bm_l = bm0; W_l = W0; g_l = g0; be_l = be0; C = 1; }
        else {
            Wm_l = Wm + (size_t)(i - 1) * 64 * 64;
            bm_l = bm + (size_t)(i - 1) * 64;
            W_l  = W  + (size_t)(i - 1) * 32 * 128;
            g_l  = g  + (size_t)(i - 1) * 32;
            be_l = be + (size_t)(i - 1) * 32;
            C = 32;
        }
        if (C == 1) k_zmax<1 ><<<dim3(4, 32, 8), 256, 0, stream>>>(Zbuf, Wm_l, pzA, pzB);
        else        k_zmax<32><<<dim3(4, 32, 8), 256, 0, stream>>>(Zbuf, Wm_l, pzA, pzB);
        k_zred<<<dim3(64, 8), 256, 0, stream>>>(pzA, pzB, bm_l, zmaxf);
        k_zmaxw<<<dim3(32, 8), 256, 0, stream>>>(zmaxf, W_l, 2 * C + 64, zmaxW);
        if (C == 1) k_conv<1 ><<<dim3(256, 8), 256, 0, stream>>>(Zbuf, W_l, zmaxW, Ybuf, pstats);
        else        k_conv<32><<<dim3(256, 8), 256, 0, stream>>>(Zbuf, W_l, zmaxW, Ybuf, pstats);
        k_reduce<<<64, 256, 0, stream>>>(pstats, stats);
        bool addk   = (i == 2 || i == 4);
        bool storek = (i % 2 == 0);
        k_bnapply<<<4096, 256, 0, stream>>>(Ybuf, stats, g_l, be_l,
                                            addk ? Zkeep : (const float*)nullptr, ap,
                                            Zbuf, storek ? Zkeep : (float*)nullptr);
    }

    k_final<<<dim3(64, 8), 256, 0, stream>>>(Zbuf, Wf, T, pfin);
    k_reduce<<<2, 256, 0, stream>>>(pfin, fstats);
    k_mm<<<256, 256, 0, stream>>>(T, fstats, gf, bf, out, MMb);
    k_rowstats<<<256, 256, 0, stream>>>(MMb, rmaxb, rsumb);
    hipMemsetAsync(ckey, 0, 1024 * 4, stream);
    hipMemsetAsync(csum, 0, 1024 * 4, stream);
    k_colmax<<<dim3(16, 4), 256, 0, stream>>>(MMb, ckey);
    k_colsum<<<dim3(16, 4), 256, 0, stream>>>(MMb, ckey, csum);
    k_agg<<<256, 256, 0, stream>>>(MMb, rmaxb, rsumb, ckey, csum, out);
}